// Round 7
// baseline (4248.425 us; speedup 1.0000x reference)
//
#include <hip/hip_runtime.h>
#include <math.h>

#define Bz 32
#define Tz 20
#define TMz 19
#define Vz 10000
#define INFLAT 262144   // P*D
#define RELSZ 16384
#define NBLK 512

// workspace float offsets
#define WS_PH     0
#define WS_PC     4194304
#define WS_ATT1   0              // reuses ph/pc region after k_reduce3
#define WS_EXPE   8388608        // 32768
#define WS_ZPART  8421376        // 512
#define WS_AWF    8421888        // 8192 (atomic-accumulated, unnormalized)
#define WS_GSG    8430080        // 5*32*256 = 40960
#define WS_HST    8471040        // 8192
#define WS_CST    8479232        // 8192
#define WS_CSTB   8487424        // 8192
#define WS_AT2G   8495616        // 8192
#define WS_INTS   8503808        // ordp[32] slp[32] barmem[64+512]
#define WS_PCHC   8504832        // 128*32*256 = 1048576

__device__ __forceinline__ float sigm(float x) { return 1.0f / (1.0f + expf(-x)); }

// Agent-scope coherent accessors (sc1: bypass per-XCD L2, no cache-wide
// invalidation needed). ALL cross-phase-communicated data goes through these;
// read-only data uses normal cached loads and stays L1/L2-hot forever.
__device__ __forceinline__ float agload(const float* p) {
    return __hip_atomic_load(p, __ATOMIC_RELAXED, __HIP_MEMORY_SCOPE_AGENT);
}
__device__ __forceinline__ void agstore(float* p, float v) {
    __hip_atomic_store(p, v, __ATOMIC_RELAXED, __HIP_MEMORY_SCOPE_AGENT);
}
__device__ __forceinline__ int agloadi(const int* p) {
    return __hip_atomic_load(p, __ATOMIC_RELAXED, __HIP_MEMORY_SCOPE_AGENT);
}
__device__ __forceinline__ void agstorei(int* p, int v) {
    __hip_atomic_store(p, v, __ATOMIC_RELAXED, __HIP_MEMORY_SCOPE_AGENT);
}
__device__ __forceinline__ void agadd(float* p, float v) {
    __hip_atomic_fetch_add(p, v, __ATOMIC_RELAXED, __HIP_MEMORY_SCOPE_AGENT);
}

__device__ __forceinline__ void gl_lds16(const float* g, float* l) {
    __builtin_amdgcn_global_load_lds(
        (const __attribute__((address_space(1))) unsigned int*)g,
        (__attribute__((address_space(3))) unsigned int*)l,
        16, 0, 0);
}

// Zero-invalidation grid barrier: per-wave vmcnt drain (write-through stores
// are globally visible once acked), slot arrive, block 0 aggregates, root
// publish. NO fences -> L1/L2 contents survive across barriers.
__device__ __forceinline__ void gbar(int* slots, int* root, int gen) {
    asm volatile("s_waitcnt vmcnt(0)" ::: "memory");
    __syncthreads();
    if (blockIdx.x == 0) {
        int i0 = threadIdx.x, i1 = threadIdx.x + 256;
        if (i0 != 0) {
            while (agloadi(&slots[i0]) < gen) __builtin_amdgcn_s_sleep(1);
        }
        while (agloadi(&slots[i1]) < gen) __builtin_amdgcn_s_sleep(1);
        __syncthreads();
        if (threadIdx.x == 0) agstorei(root, gen);
    } else if (threadIdx.x == 0) {
        agstorei(&slots[blockIdx.x], gen);
        while (agloadi(root) < gen) __builtin_amdgcn_s_sleep(2);
    }
    __syncthreads();
    asm volatile("" ::: "memory");
}

// ---------------- sort + barrier init ----------------
__global__ void k_sort(const int* __restrict__ lens, float* __restrict__ out_order,
                       int* __restrict__ ord, int* __restrict__ sentlen, int* __restrict__ barmem) {
    if (threadIdx.x == 0 && blockIdx.x == 0) {
        for (int i = 0; i < 64 + NBLK; ++i) barmem[i] = 0;
        int l[Bz]; bool used[Bz];
        for (int b = 0; b < Bz; ++b) { l[b] = lens[b]; used[b] = false; }
        for (int i = 0; i < Bz; ++i) {
            int best = -1;
            for (int j = 0; j < Bz; ++j)
                if (!used[j] && (best < 0 || l[j] > l[best])) best = j;
            used[best] = true;
            ord[i] = best;
            sentlen[i] = l[best] - 1;
            out_order[i] = (float)best;
        }
    }
}

// ---------------- h0,c0: flat(32,262144) @ W_ih / W_ic ----------------
__global__ __launch_bounds__(256) void k_gemv2(const float* __restrict__ X, const int* __restrict__ ord,
                                               const float* __restrict__ W1, const float* __restrict__ W2,
                                               float* __restrict__ p1, float* __restrict__ p2) {
    __shared__ __align__(16) float wlds[8192];
    __shared__ __align__(16) float xsT[256 * 36];
    __shared__ int ords[32];
    int tid = threadIdx.x;
    int wv = tid >> 6, ln = tid & 63;
    size_t k0 = (size_t)blockIdx.x * 512;

    if (tid < 32) ords[tid] = ord[tid];
    __syncthreads();

    auto stage_xs = [&](int hh) {
        for (int idx = tid; idx < 2048; idx += 256) {
            int b = idx >> 6, kq = idx & 63;
            float4 v = *(const float4*)&X[(size_t)ords[b] * INFLAT + k0 + (size_t)hh * 256 + kq * 4];
            xsT[(kq * 4 + 0) * 36 + b] = v.x;
            xsT[(kq * 4 + 1) * 36 + b] = v.y;
            xsT[(kq * 4 + 2) * 36 + b] = v.z;
            xsT[(kq * 4 + 3) * 36 + b] = v.w;
        }
    };
    auto issue = [&](int n) {
        int slot = n & 1;
        size_t krow = k0 + (size_t)n * 8 + wv * 2;
        const float* g1 = W1 + krow * 256 + ln * 4;
        const float* g2 = W2 + krow * 256 + ln * 4;
        float* l1 = &wlds[slot * 4096 + (wv * 2) * 256 + ln * 4];
        float* l2 = &wlds[slot * 4096 + 2048 + (wv * 2) * 256 + ln * 4];
        gl_lds16(g1, l1);
        gl_lds16(g2, l2);
        gl_lds16(g1 + 256, l1 + 256);
        gl_lds16(g2 + 256, l2 + 256);
    };

    float ah[32], ac[32];
#pragma unroll
    for (int b = 0; b < 32; ++b) { ah[b] = 0.f; ac[b] = 0.f; }

    stage_xs(0);
    issue(0);

#pragma unroll 1
    for (int c = 0; c < 64; ++c) {
        if (c == 32) stage_xs(1);
        if (c + 1 < 64) {
            issue(c + 1);
            asm volatile("s_waitcnt vmcnt(4)" ::: "memory");
        } else {
            asm volatile("s_waitcnt vmcnt(0)" ::: "memory");
        }
        __syncthreads();
        int slot = c & 1;
        int xb0 = (c & 31) * 8;
#pragma unroll
        for (int kk = 0; kk < 8; ++kk) {
            float w1 = wlds[slot * 4096 + kk * 256 + tid];
            float w2 = wlds[slot * 4096 + 2048 + kk * 256 + tid];
            const float4* xr = (const float4*)&xsT[(xb0 + kk) * 36];
#pragma unroll
            for (int bq = 0; bq < 8; ++bq) {
                float4 x4 = xr[bq];
                ah[bq * 4 + 0] += x4.x * w1; ac[bq * 4 + 0] += x4.x * w2;
                ah[bq * 4 + 1] += x4.y * w1; ac[bq * 4 + 1] += x4.y * w2;
                ah[bq * 4 + 2] += x4.z * w1; ac[bq * 4 + 2] += x4.z * w2;
                ah[bq * 4 + 3] += x4.w * w1; ac[bq * 4 + 3] += x4.w * w2;
            }
        }
        __syncthreads();
    }
#pragma unroll
    for (int b = 0; b < 32; ++b) {
        size_t o = ((size_t)blockIdx.x * 32 + b) * 256 + tid;
        p1[o] = ah[b];
        p2[o] = ac[b];
    }
}

// ---------------- C0: rel(32,16384) @ W_iC, split-K ----------------
__global__ __launch_bounds__(256) void k_gemvC(const float* __restrict__ R, const int* __restrict__ ord,
                                               const float* __restrict__ W, float* __restrict__ p) {
    __shared__ float xs[32 * 128];
    __shared__ int ords[32];
    int tid = threadIdx.x, bx = blockIdx.x;
    if (tid < 32) ords[tid] = ord[tid];
    __syncthreads();
    int k0 = bx * 128;
    for (int idx = tid; idx < 32 * 128; idx += 256) {
        int b = idx >> 7, kk = idx & 127;
        xs[idx] = R[(size_t)ords[b] * RELSZ + k0 + kk];
    }
    __syncthreads();
    float acc[32];
#pragma unroll
    for (int b = 0; b < 32; ++b) acc[b] = 0.f;
    for (int kk = 0; kk < 128; ++kk) {
        float w = W[(size_t)(k0 + kk) * 256 + tid];
#pragma unroll
        for (int b = 0; b < 32; ++b) acc[b] += xs[b * 128 + kk] * w;
    }
#pragma unroll
    for (int b = 0; b < 32; ++b) p[((size_t)bx * 32 + b) * 256 + tid] = acc[b];
}

// ---------------- combined split-K reduces: h0, c0, C0 ----------------
__global__ __launch_bounds__(256) void k_reduce3(const float* __restrict__ ph, const float* __restrict__ pc,
                                                 const float* __restrict__ pC,
                                                 const float* __restrict__ b_ih, const float* __restrict__ b_ic,
                                                 const float* __restrict__ b_iC,
                                                 float* __restrict__ hst, float* __restrict__ cst,
                                                 float* __restrict__ Cst) {
    int which = blockIdx.x >> 5, b = blockIdx.x & 31, j = threadIdx.x;
    if (which == 0) {
        float s0 = b_ih[j], s1 = 0.f, s2 = 0.f, s3 = 0.f;
        for (int c = 0; c < 512; c += 4) {
            s0 += ph[((size_t)((c + 0) * 32 + b)) * 256 + j];
            s1 += ph[((size_t)((c + 1) * 32 + b)) * 256 + j];
            s2 += ph[((size_t)((c + 2) * 32 + b)) * 256 + j];
            s3 += ph[((size_t)((c + 3) * 32 + b)) * 256 + j];
        }
        hst[b * 256 + j] = s0 + s1 + s2 + s3;
    } else if (which == 1) {
        float s0 = b_ic[j], s1 = 0.f, s2 = 0.f, s3 = 0.f;
        for (int c = 0; c < 512; c += 4) {
            s0 += pc[((size_t)((c + 0) * 32 + b)) * 256 + j];
            s1 += pc[((size_t)((c + 1) * 32 + b)) * 256 + j];
            s2 += pc[((size_t)((c + 2) * 32 + b)) * 256 + j];
            s3 += pc[((size_t)((c + 3) * 32 + b)) * 256 + j];
        }
        cst[b * 256 + j] = s0 + s1 + s2 + s3;
    } else {
        float s0 = b_iC[j], s1 = 0.f, s2 = 0.f, s3 = 0.f;
        for (int c = 0; c < 128; c += 4) {
            s0 += pC[((size_t)((c + 0) * 32 + b)) * 256 + j];
            s1 += pC[((size_t)((c + 1) * 32 + b)) * 256 + j];
            s2 += pC[((size_t)((c + 2) * 32 + b)) * 256 + j];
            s3 += pC[((size_t)((c + 3) * 32 + b)) * 256 + j];
        }
        Cst[b * 256 + j] = s0 + s1 + s2 + s3;
    }
}

// ---------------- initial at2g = h0 @ W_dec + b_dec (4 blocks) + awf zero ----------------
__global__ __launch_bounds__(256) void k_at2g0(const float* __restrict__ hst, const float* __restrict__ W_dec,
                                               const float* __restrict__ b_dec, float* __restrict__ at2g,
                                               float* __restrict__ awf) {
    __shared__ __align__(16) float hs[8192];
    int tid = threadIdx.x;
    for (int i = blockIdx.x * 256 + tid; i < 8192; i += 1024) awf[i] = 0.f;
    for (int i = tid; i < 2048; i += 256) ((float4*)hs)[i] = ((const float4*)hst)[i];
    __syncthreads();
    int col = blockIdx.x * 64 + (tid & 63), bg = tid >> 6;
    float acc[8] = {0.f,0.f,0.f,0.f,0.f,0.f,0.f,0.f};
    for (int k = 0; k < 256; ++k) {
        float w = W_dec[(size_t)k * 256 + col];
#pragma unroll
        for (int bi = 0; bi < 8; ++bi) acc[bi] += hs[(bg * 8 + bi) * 256 + k] * w;
    }
    float bd = b_dec[col];
#pragma unroll
    for (int bi = 0; bi < 8; ++bi) at2g[(bg * 8 + bi) * 256 + col] = acc[bi] + bd;
}

// ---------------- att1 = info_sorted @ W_enc + b_enc ----------------
__global__ __launch_bounds__(256) void k_att1(const float* __restrict__ info, const int* __restrict__ ord,
                                              const float* __restrict__ W, const float* __restrict__ bias,
                                              float* __restrict__ att1) {
    __shared__ __align__(16) float xsT[256 * 36];
    int tid = threadIdx.x;
    int r0 = blockIdx.x * 32;
    int b = r0 >> 10, p0 = r0 & 1023;
    const float* src = info + (size_t)ord[b] * INFLAT + (size_t)p0 * 256;
    for (int idx = tid; idx < 2048; idx += 256) {
        int r = idx >> 6, kq = idx & 63;
        float4 v = *(const float4*)&src[r * 256 + kq * 4];
        xsT[(kq * 4 + 0) * 36 + r] = v.x;
        xsT[(kq * 4 + 1) * 36 + r] = v.y;
        xsT[(kq * 4 + 2) * 36 + r] = v.z;
        xsT[(kq * 4 + 3) * 36 + r] = v.w;
    }
    __syncthreads();
    float acc[32];
#pragma unroll
    for (int r = 0; r < 32; ++r) acc[r] = 0.f;
    for (int k = 0; k < 256; ++k) {
        float w = W[k * 256 + tid];
        const float4* xr = (const float4*)&xsT[k * 36];
#pragma unroll
        for (int rq = 0; rq < 8; ++rq) {
            float4 x4 = xr[rq];
            acc[rq * 4 + 0] += x4.x * w;
            acc[rq * 4 + 1] += x4.y * w;
            acc[rq * 4 + 2] += x4.z * w;
            acc[rq * 4 + 3] += x4.w * w;
        }
    }
    float bj = bias[tid];
#pragma unroll
    for (int r = 0; r < 32; ++r) att1[((size_t)(r0 + r)) * 256 + tid] = acc[r] + bj;
}

// ---------------- fused steps kernel ----------------
struct KArgs {
    const float *info, *emb, *W_dec, *b_dec, *W_full, *b_full;
    const float *W_i, *W_f, *W_o, *W_g1, *W_g2;
    const float *b_i, *b_f, *b_o, *b_g1, *b_g2;
    const float *W_mlp, *b_mlp, *W_fc, *b_fc;
    const int *caps;
    float *att1, *expe, *zpart, *awf, *gsg, *hst, *cst, *Cst, *at2g;
    const int *ord, *slp;
    int *root, *slots;
    float *out_pred, *out_alpha;
};

// h staged fresh via agload (hst is communicated data)
__device__ void pred_task2(const KArgs& a, float* sm, int tile, int tm1) {
    int tid = threadIdx.x;
    for (int i = tid; i < 8192; i += 256) sm[i] = agload(&a.hst[i]);
    __syncthreads();
    int col = tile * 64 + (tid & 63), bg = tid >> 6;
    if (col >= Vz) return;
    float acc[8] = {0.f, 0.f, 0.f, 0.f, 0.f, 0.f, 0.f, 0.f};
    for (int jq = 0; jq < 64; ++jq) {
        float w0 = a.W_fc[(size_t)(jq * 4 + 0) * Vz + col];
        float w1 = a.W_fc[(size_t)(jq * 4 + 1) * Vz + col];
        float w2 = a.W_fc[(size_t)(jq * 4 + 2) * Vz + col];
        float w3 = a.W_fc[(size_t)(jq * 4 + 3) * Vz + col];
#pragma unroll
        for (int bi = 0; bi < 8; ++bi) {
            float4 h4 = *(const float4*)&sm[(bg * 8 + bi) * 256 + jq * 4];
            acc[bi] += h4.x * w0 + h4.y * w1 + h4.z * w2 + h4.w * w3;
        }
    }
    float bv = a.b_fc[col];
#pragma unroll
    for (int bi = 0; bi < 8; ++bi) {
        int b = bg * 8 + bi;
        float r = (a.slp[b] > tm1) ? (acc[bi] + bv) : 0.f;
        a.out_pred[((size_t)b * TMz + tm1) * Vz + col] = r;
    }
}

__global__ __launch_bounds__(256, 2) void k_steps(KArgs a) {
    __shared__ __align__(16) float sm[8224];
    __shared__ int caps_s[32];
    int bid = blockIdx.x, tid = threadIdx.x;
    int b = bid >> 4, sub = bid & 15;
    int gen = 0;

    for (int t = 0; t < TMz; ++t) {
        // ---------- PA: e + expe + zpart + awf-accumulate (all 512 blocks) ----------
        {
            sm[tid] = agload(&a.at2g[b * 256 + tid]);
            sm[256 + tid] = a.W_full[tid];
            __syncthreads();
            int pl = tid & 63, kq = tid >> 6;
            const float* row = a.att1 + ((size_t)(b * 1024 + sub * 64 + pl)) * 256 + kq * 64;
            const float* a2 = sm + kq * 64;
            const float* wf = sm + 256 + kq * 64;
            float part = 0.f;
#pragma unroll
            for (int q = 0; q < 16; ++q) {
                float4 r4 = *(const float4*)&row[q * 4];
                part += fmaxf(r4.x + a2[q * 4 + 0], 0.f) * wf[q * 4 + 0]
                      + fmaxf(r4.y + a2[q * 4 + 1], 0.f) * wf[q * 4 + 1]
                      + fmaxf(r4.z + a2[q * 4 + 2], 0.f) * wf[q * 4 + 2]
                      + fmaxf(r4.w + a2[q * 4 + 3], 0.f) * wf[q * 4 + 3];
            }
            sm[512 + kq * 64 + pl] = part;
            __syncthreads();
            if (tid < 64) {
                float e = sm[512 + tid] + sm[576 + tid] + sm[640 + tid] + sm[704 + tid] + a.b_full[0];
                float ex = expf(e);
                agstore(&a.expe[b * 1024 + sub * 64 + tid], ex);
                sm[768 + tid] = ex;
                float s = ex;
                s += __shfl_down(s, 32); s += __shfl_down(s, 16); s += __shfl_down(s, 8);
                s += __shfl_down(s, 4);  s += __shfl_down(s, 2);  s += __shfl_down(s, 1);
                if (tid == 0) agstore(&a.zpart[b * 16 + sub], s);
            }
            __syncthreads();
            const float* ib = a.info + (size_t)a.ord[b] * INFLAT + (size_t)(sub * 64) * 256;
            const float* ex = sm + 768;
            float q0=0.f,q1=0.f,q2=0.f,q3=0.f,q4=0.f,q5=0.f,q6=0.f,q7=0.f;
            for (int i = 0; i < 64; i += 8) {
                q0 += ex[i+0] * ib[(size_t)(i+0) * 256 + tid];
                q1 += ex[i+1] * ib[(size_t)(i+1) * 256 + tid];
                q2 += ex[i+2] * ib[(size_t)(i+2) * 256 + tid];
                q3 += ex[i+3] * ib[(size_t)(i+3) * 256 + tid];
                q4 += ex[i+4] * ib[(size_t)(i+4) * 256 + tid];
                q5 += ex[i+5] * ib[(size_t)(i+5) * 256 + tid];
                q6 += ex[i+6] * ib[(size_t)(i+6) * 256 + tid];
                q7 += ex[i+7] * ib[(size_t)(i+7) * 256 + tid];
            }
            agadd(&a.awf[b * 256 + tid], ((q0+q1)+(q2+q3)) + ((q4+q5)+(q6+q7)));
        }
        gbar(a.slots, a.root, ++gen);

        // ---------- PB: gates (0..19) | alpha (20..51) | pred(t-1) (52..208) ----------
        if (bid < 20) {
            int g = bid >> 2, ct = bid & 3;
            const float* Wg  = (g == 0) ? a.W_i : (g == 1) ? a.W_f : (g == 2) ? a.W_o : (g == 3) ? a.W_g1 : a.W_g2;
            const float* bgp = (g == 0) ? a.b_i : (g == 1) ? a.b_f : (g == 2) ? a.b_o : (g == 3) ? a.b_g1 : a.b_g2;
            if (tid < 32) {
                float Z = 0.f;
#pragma unroll
                for (int c = 0; c < 16; ++c) Z += agload(&a.zpart[tid * 16 + c]);
                sm[8192 + tid] = 1.0f / Z;
            }
            if (tid >= 64 && tid < 96) caps_s[tid - 64] = a.caps[a.ord[tid - 64] * Tz + t];
            __syncthreads();
            int col = ct * 64 + (tid & 63), bg = tid >> 6;
            float acc[8];
            float bb0 = bgp[col];
#pragma unroll
            for (int bi = 0; bi < 8; ++bi) acc[bi] = bb0;
            for (int kc = 0; kc < 4; ++kc) {
                __syncthreads();
                for (int idx = tid; idx < 8192; idx += 256) {
                    int b2 = idx >> 8, kk = idx & 255;
                    float v;
                    if (kc < 2)       v = a.emb[(size_t)caps_s[b2] * 512 + kc * 256 + kk];
                    else if (kc == 2) v = agload(&a.awf[b2 * 256 + kk]) * sm[8192 + b2];
                    else              v = agload(&a.hst[b2 * 256 + kk]);
                    sm[idx] = v;
                }
                __syncthreads();
                int kbase = kc * 256;
                for (int kk = 0; kk < 256; kk += 4) {
                    float w0 = Wg[(size_t)(kbase + kk + 0) * 256 + col];
                    float w1 = Wg[(size_t)(kbase + kk + 1) * 256 + col];
                    float w2 = Wg[(size_t)(kbase + kk + 2) * 256 + col];
                    float w3 = Wg[(size_t)(kbase + kk + 3) * 256 + col];
#pragma unroll
                    for (int bi = 0; bi < 8; ++bi) {
                        float4 x4 = *(const float4*)&sm[(bg * 8 + bi) * 256 + kk];
                        acc[bi] += x4.x * w0 + x4.y * w1 + x4.z * w2 + x4.w * w3;
                    }
                }
            }
#pragma unroll
            for (int bi = 0; bi < 8; ++bi)
                agstore(&a.gsg[((size_t)(g * 32 + bg * 8 + bi)) * 256 + col], acc[bi]);
        } else if (bid < 52) {
            int bb = bid - 20;
            float Z = 0.f;
#pragma unroll
            for (int c = 0; c < 16; ++c) Z += agload(&a.zpart[bb * 16 + c]);
            float invZ = 1.0f / Z;
            float am = (a.slp[bb] > t) ? invZ : 0.f;
            float* oal = a.out_alpha + ((size_t)bb * TMz + t) * 1024;
            for (int p = tid; p < 1024; p += 256) oal[p] = agload(&a.expe[bb * 1024 + p]) * am;
        } else if (t > 0 && bid < 209) {
            pred_task2(a, sm, bid - 52, t - 1);
        }
        gbar(a.slots, a.root, ++gen);

        // ---------- PC: cell + mlp + h + at2(next) + awf-zero (32 blocks) ----------
        if (bid < 32) {
            int bb = bid, j = tid;
            agstore(&a.awf[bb * 256 + j], 0.f);
            float giv = agload(&a.gsg[((size_t)(0 * 32 + bb)) * 256 + j]);
            float gfv = agload(&a.gsg[((size_t)(1 * 32 + bb)) * 256 + j]);
            float gov = agload(&a.gsg[((size_t)(2 * 32 + bb)) * 256 + j]);
            float gg1 = agload(&a.gsg[((size_t)(3 * 32 + bb)) * 256 + j]);
            float gg2 = agload(&a.gsg[((size_t)(4 * 32 + bb)) * 256 + j]);
            float iv = sigm(giv), fv = sigm(gfv), ov = sigm(gov);
            float g1 = tanhf(gg1), g2 = tanhf(gg2);
            float nc = fv * a.cst[bb * 256 + j] + iv * g1;
            float nC = fv * a.Cst[bb * 256 + j] + iv * g2;
            a.cst[bb * 256 + j] = nc;
            a.Cst[bb * 256 + j] = nC;
            sm[j] = nc;
            sm[256 + j] = nC;
            __syncthreads();
            float m0 = a.b_mlp[j], m1=0.f, m2=0.f, m3=0.f, m4=0.f, m5=0.f, m6=0.f, m7=0.f;
            for (int k = 0; k < 512; k += 8) {
                m0 += sm[k+0] * a.W_mlp[(size_t)(k+0) * 256 + j];
                m1 += sm[k+1] * a.W_mlp[(size_t)(k+1) * 256 + j];
                m2 += sm[k+2] * a.W_mlp[(size_t)(k+2) * 256 + j];
                m3 += sm[k+3] * a.W_mlp[(size_t)(k+3) * 256 + j];
                m4 += sm[k+4] * a.W_mlp[(size_t)(k+4) * 256 + j];
                m5 += sm[k+5] * a.W_mlp[(size_t)(k+5) * 256 + j];
                m6 += sm[k+6] * a.W_mlp[(size_t)(k+6) * 256 + j];
                m7 += sm[k+7] * a.W_mlp[(size_t)(k+7) * 256 + j];
            }
            float hv = ov * tanhf(((m0+m1)+(m2+m3)) + ((m4+m5)+(m6+m7)));
            agstore(&a.hst[bb * 256 + j], hv);
            sm[512 + j] = hv;
            __syncthreads();
            float a0 = a.b_dec[j], a1=0.f, a2=0.f, a3=0.f, a4=0.f, a5=0.f, a6=0.f, a7=0.f;
            for (int k = 0; k < 256; k += 8) {
                a0 += sm[512 + k+0] * a.W_dec[(size_t)(k+0) * 256 + j];
                a1 += sm[512 + k+1] * a.W_dec[(size_t)(k+1) * 256 + j];
                a2 += sm[512 + k+2] * a.W_dec[(size_t)(k+2) * 256 + j];
                a3 += sm[512 + k+3] * a.W_dec[(size_t)(k+3) * 256 + j];
                a4 += sm[512 + k+4] * a.W_dec[(size_t)(k+4) * 256 + j];
                a5 += sm[512 + k+5] * a.W_dec[(size_t)(k+5) * 256 + j];
                a6 += sm[512 + k+6] * a.W_dec[(size_t)(k+6) * 256 + j];
                a7 += sm[512 + k+7] * a.W_dec[(size_t)(k+7) * 256 + j];
            }
            agstore(&a.at2g[bb * 256 + j], ((a0+a1)+(a2+a3)) + ((a4+a5)+(a6+a7)));
        }
        gbar(a.slots, a.root, ++gen);
    }

    // epilogue: pred for t = 18
    if (bid >= 52 && bid < 209) pred_task2(a, sm, bid - 52, TMz - 1);
}

extern "C" void kernel_launch(void* const* d_in, const int* in_sizes, int n_in,
                              void* d_out, int out_size, void* d_ws, size_t ws_size,
                              hipStream_t stream) {
    const float* info  = (const float*)d_in[0];
    const float* rel   = (const float*)d_in[1];
    const int*   caps  = (const int*)d_in[2];
    const int*   lens  = (const int*)d_in[3];
    const float* emb   = (const float*)d_in[4];
    const float* W_enc = (const float*)d_in[5];
    const float* b_enc = (const float*)d_in[6];
    const float* W_dec = (const float*)d_in[7];
    const float* b_dec = (const float*)d_in[8];
    const float* W_full= (const float*)d_in[9];
    const float* b_full= (const float*)d_in[10];
    const float* W_i   = (const float*)d_in[11];
    const float* b_i   = (const float*)d_in[12];
    const float* W_f   = (const float*)d_in[13];
    const float* b_f   = (const float*)d_in[14];
    const float* W_o   = (const float*)d_in[15];
    const float* b_o   = (const float*)d_in[16];
    const float* W_g1  = (const float*)d_in[17];
    const float* b_g1  = (const float*)d_in[18];
    const float* W_g2  = (const float*)d_in[19];
    const float* b_g2  = (const float*)d_in[20];
    const float* W_mlp = (const float*)d_in[21];
    const float* b_mlp = (const float*)d_in[22];
    const float* W_fc  = (const float*)d_in[25];
    const float* b_fc  = (const float*)d_in[26];
    const float* W_ih  = (const float*)d_in[27];
    const float* b_ih  = (const float*)d_in[28];
    const float* W_ic  = (const float*)d_in[29];
    const float* b_ic  = (const float*)d_in[30];
    const float* W_iC  = (const float*)d_in[31];
    const float* b_iC  = (const float*)d_in[32];

    float* out = (float*)d_out;
    float* out_pred  = out;
    float* out_alpha = out + (size_t)Bz * TMz * Vz;
    float* out_order = out_alpha + (size_t)Bz * TMz * 1024;

    float* w = (float*)d_ws;
    float* ph   = w + WS_PH;
    float* pcp  = w + WS_PC;
    float* att1 = w + WS_ATT1;
    float* expe = w + WS_EXPE;
    float* zpart= w + WS_ZPART;
    float* awf  = w + WS_AWF;
    float* gsg  = w + WS_GSG;
    float* hst  = w + WS_HST;
    float* cst  = w + WS_CST;
    float* Cst  = w + WS_CSTB;
    float* at2g = w + WS_AT2G;
    int*   ordp = (int*)(w + WS_INTS);
    int*   slp  = ordp + 32;
    int*   barmem = ordp + 64;
    float* pC   = w + WS_PCHC;

    k_sort<<<1, 64, 0, stream>>>(lens, out_order, ordp, slp, barmem);
    k_gemv2<<<512, 256, 0, stream>>>(info, ordp, W_ih, W_ic, ph, pcp);
    k_gemvC<<<128, 256, 0, stream>>>(rel, ordp, W_iC, pC);
    k_reduce3<<<96, 256, 0, stream>>>(ph, pcp, pC, b_ih, b_ic, b_iC, hst, cst, Cst);
    k_at2g0<<<4, 256, 0, stream>>>(hst, W_dec, b_dec, at2g, awf);
    k_att1<<<1024, 256, 0, stream>>>(info, ordp, W_enc, b_enc, att1);

    KArgs ka;
    ka.info = info; ka.emb = emb; ka.W_dec = W_dec; ka.b_dec = b_dec;
    ka.W_full = W_full; ka.b_full = b_full;
    ka.W_i = W_i; ka.W_f = W_f; ka.W_o = W_o; ka.W_g1 = W_g1; ka.W_g2 = W_g2;
    ka.b_i = b_i; ka.b_f = b_f; ka.b_o = b_o; ka.b_g1 = b_g1; ka.b_g2 = b_g2;
    ka.W_mlp = W_mlp; ka.b_mlp = b_mlp; ka.W_fc = W_fc; ka.b_fc = b_fc;
    ka.caps = caps;
    ka.att1 = att1; ka.expe = expe; ka.zpart = zpart; ka.awf = awf;
    ka.gsg = gsg; ka.hst = hst; ka.cst = cst; ka.Cst = Cst; ka.at2g = at2g;
    ka.ord = ordp; ka.slp = slp;
    ka.root = barmem; ka.slots = barmem + 64;
    ka.out_pred = out_pred; ka.out_alpha = out_alpha;

    k_steps<<<NBLK, 256, 0, stream>>>(ka);
}

// Round 9
// 2496.966 us; speedup vs baseline: 1.7014x; 1.7014x over previous
//
#include <hip/hip_runtime.h>
#include <math.h>

#define Bz 32
#define Tz 20
#define TMz 19
#define Vz 10000
#define INFLAT 262144   // P*D
#define RELSZ 16384
#define NBLK 512

// workspace float offsets
#define WS_PH     0
#define WS_PC     4194304
#define WS_ATT1   0              // reuses ph/pc region after k_reduce3
#define WS_EXPE   8388608        // 32768
#define WS_ZPART  8421376        // 512
#define WS_AWF    8421888        // 8192 (atomic-accumulated, unnormalized)
#define WS_GSP    8430080        // 5*4*32*256 = 163840
#define WS_HST    8593920        // 8192
#define WS_CST0   8602112        // 8192
#define WS_CSTB0  8610304        // 8192
#define WS_CST1   8618496        // 8192
#define WS_CSTB1  8626688        // 8192
#define WS_AT2P   8634880        // 8*32*256 = 65536
#define WS_INTS   8700416        // ordp[32] slp[32] barmem[64+512]
#define WS_PCHC   8701440        // 128*32*256 = 1048576

__device__ __forceinline__ float sigm(float x) { return 1.0f / (1.0f + expf(-x)); }

// Agent-scope accessors for cross-block-communicated state ONLY.
__device__ __forceinline__ float agload(const float* p) {
    return __hip_atomic_load(p, __ATOMIC_RELAXED, __HIP_MEMORY_SCOPE_AGENT);
}
__device__ __forceinline__ void agstore(float* p, float v) {
    __hip_atomic_store(p, v, __ATOMIC_RELAXED, __HIP_MEMORY_SCOPE_AGENT);
}
__device__ __forceinline__ int agloadi(const int* p) {
    return __hip_atomic_load(p, __ATOMIC_RELAXED, __HIP_MEMORY_SCOPE_AGENT);
}
__device__ __forceinline__ void agstorei(int* p, int v) {
    __hip_atomic_store(p, v, __ATOMIC_RELAXED, __HIP_MEMORY_SCOPE_AGENT);
}
__device__ __forceinline__ void agadd(float* p, float v) {
    __hip_atomic_fetch_add(p, v, __ATOMIC_RELAXED, __HIP_MEMORY_SCOPE_AGENT);
}

__device__ __forceinline__ void gl_lds16(const float* g, float* l) {
    __builtin_amdgcn_global_load_lds(
        (const __attribute__((address_space(1))) unsigned int*)g,
        (__attribute__((address_space(3))) unsigned int*)l,
        16, 0, 0);
}

// Fence-free slot grid barrier (no cache invalidation).
__device__ __forceinline__ void gbar(int* slots, int* root, int gen) {
    asm volatile("s_waitcnt vmcnt(0)" ::: "memory");
    __syncthreads();
    if (blockIdx.x == 0) {
        int i0 = threadIdx.x, i1 = threadIdx.x + 256;
        if (i0 != 0) {
            while (agloadi(&slots[i0]) < gen) __builtin_amdgcn_s_sleep(1);
        }
        while (agloadi(&slots[i1]) < gen) __builtin_amdgcn_s_sleep(1);
        __syncthreads();
        if (threadIdx.x == 0) agstorei(root, gen);
    } else if (threadIdx.x == 0) {
        agstorei(&slots[blockIdx.x], gen);
        while (agloadi(root) < gen) __builtin_amdgcn_s_sleep(2);
    }
    __syncthreads();
    asm volatile("" ::: "memory");
}

// ---------------- sort + barrier init ----------------
__global__ void k_sort(const int* __restrict__ lens, float* __restrict__ out_order,
                       int* __restrict__ ord, int* __restrict__ sentlen, int* __restrict__ barmem) {
    if (threadIdx.x == 0 && blockIdx.x == 0) {
        for (int i = 0; i < 64 + NBLK; ++i) barmem[i] = 0;
        int l[Bz]; bool used[Bz];
        for (int b = 0; b < Bz; ++b) { l[b] = lens[b]; used[b] = false; }
        for (int i = 0; i < Bz; ++i) {
            int best = -1;
            for (int j = 0; j < Bz; ++j)
                if (!used[j] && (best < 0 || l[j] > l[best])) best = j;
            used[best] = true;
            ord[i] = best;
            sentlen[i] = l[best] - 1;
            out_order[i] = (float)best;
        }
    }
}

// ---------------- h0,c0: flat(32,262144) @ W_ih / W_ic ----------------
__global__ __launch_bounds__(256) void k_gemv2(const float* __restrict__ X, const int* __restrict__ ord,
                                               const float* __restrict__ W1, const float* __restrict__ W2,
                                               float* __restrict__ p1, float* __restrict__ p2) {
    __shared__ __align__(16) float wlds[8192];
    __shared__ __align__(16) float xsT[256 * 36];
    __shared__ int ords[32];
    int tid = threadIdx.x;
    int wv = tid >> 6, ln = tid & 63;
    size_t k0 = (size_t)blockIdx.x * 512;

    if (tid < 32) ords[tid] = ord[tid];
    __syncthreads();

    auto stage_xs = [&](int hh) {
        for (int idx = tid; idx < 2048; idx += 256) {
            int b = idx >> 6, kq = idx & 63;
            float4 v = *(const float4*)&X[(size_t)ords[b] * INFLAT + k0 + (size_t)hh * 256 + kq * 4];
            xsT[(kq * 4 + 0) * 36 + b] = v.x;
            xsT[(kq * 4 + 1) * 36 + b] = v.y;
            xsT[(kq * 4 + 2) * 36 + b] = v.z;
            xsT[(kq * 4 + 3) * 36 + b] = v.w;
        }
    };
    auto issue = [&](int n) {
        int slot = n & 1;
        size_t krow = k0 + (size_t)n * 8 + wv * 2;
        const float* g1 = W1 + krow * 256 + ln * 4;
        const float* g2 = W2 + krow * 256 + ln * 4;
        float* l1 = &wlds[slot * 4096 + (wv * 2) * 256 + ln * 4];
        float* l2 = &wlds[slot * 4096 + 2048 + (wv * 2) * 256 + ln * 4];
        gl_lds16(g1, l1);
        gl_lds16(g2, l2);
        gl_lds16(g1 + 256, l1 + 256);
        gl_lds16(g2 + 256, l2 + 256);
    };

    float ah[32], ac[32];
#pragma unroll
    for (int b = 0; b < 32; ++b) { ah[b] = 0.f; ac[b] = 0.f; }

    stage_xs(0);
    issue(0);

#pragma unroll 1
    for (int c = 0; c < 64; ++c) {
        if (c == 32) stage_xs(1);
        if (c + 1 < 64) {
            issue(c + 1);
            asm volatile("s_waitcnt vmcnt(4)" ::: "memory");
        } else {
            asm volatile("s_waitcnt vmcnt(0)" ::: "memory");
        }
        __syncthreads();
        int slot = c & 1;
        int xb0 = (c & 31) * 8;
#pragma unroll
        for (int kk = 0; kk < 8; ++kk) {
            float w1 = wlds[slot * 4096 + kk * 256 + tid];
            float w2 = wlds[slot * 4096 + 2048 + kk * 256 + tid];
            const float4* xr = (const float4*)&xsT[(xb0 + kk) * 36];
#pragma unroll
            for (int bq = 0; bq < 8; ++bq) {
                float4 x4 = xr[bq];
                ah[bq * 4 + 0] += x4.x * w1; ac[bq * 4 + 0] += x4.x * w2;
                ah[bq * 4 + 1] += x4.y * w1; ac[bq * 4 + 1] += x4.y * w2;
                ah[bq * 4 + 2] += x4.z * w1; ac[bq * 4 + 2] += x4.z * w2;
                ah[bq * 4 + 3] += x4.w * w1; ac[bq * 4 + 3] += x4.w * w2;
            }
        }
        __syncthreads();
    }
#pragma unroll
    for (int b = 0; b < 32; ++b) {
        size_t o = ((size_t)blockIdx.x * 32 + b) * 256 + tid;
        p1[o] = ah[b];
        p2[o] = ac[b];
    }
}

// ---------------- C0: rel(32,16384) @ W_iC, split-K ----------------
__global__ __launch_bounds__(256) void k_gemvC(const float* __restrict__ R, const int* __restrict__ ord,
                                               const float* __restrict__ W, float* __restrict__ p) {
    __shared__ float xs[32 * 128];
    __shared__ int ords[32];
    int tid = threadIdx.x, bx = blockIdx.x;
    if (tid < 32) ords[tid] = ord[tid];
    __syncthreads();
    int k0 = bx * 128;
    for (int idx = tid; idx < 32 * 128; idx += 256) {
        int b = idx >> 7, kk = idx & 127;
        xs[idx] = R[(size_t)ords[b] * RELSZ + k0 + kk];
    }
    __syncthreads();
    float acc[32];
#pragma unroll
    for (int b = 0; b < 32; ++b) acc[b] = 0.f;
    for (int kk = 0; kk < 128; ++kk) {
        float w = W[(size_t)(k0 + kk) * 256 + tid];
#pragma unroll
        for (int b = 0; b < 32; ++b) acc[b] += xs[b * 128 + kk] * w;
    }
#pragma unroll
    for (int b = 0; b < 32; ++b) p[((size_t)bx * 32 + b) * 256 + tid] = acc[b];
}

// ---------------- combined split-K reduces: h0, c0, C0 ----------------
__global__ __launch_bounds__(256) void k_reduce3(const float* __restrict__ ph, const float* __restrict__ pc,
                                                 const float* __restrict__ pC,
                                                 const float* __restrict__ b_ih, const float* __restrict__ b_ic,
                                                 const float* __restrict__ b_iC,
                                                 float* __restrict__ hst, float* __restrict__ cst,
                                                 float* __restrict__ Cst) {
    int which = blockIdx.x >> 5, b = blockIdx.x & 31, j = threadIdx.x;
    if (which == 0) {
        float s0 = b_ih[j], s1 = 0.f, s2 = 0.f, s3 = 0.f;
        for (int c = 0; c < 512; c += 4) {
            s0 += ph[((size_t)((c + 0) * 32 + b)) * 256 + j];
            s1 += ph[((size_t)((c + 1) * 32 + b)) * 256 + j];
            s2 += ph[((size_t)((c + 2) * 32 + b)) * 256 + j];
            s3 += ph[((size_t)((c + 3) * 32 + b)) * 256 + j];
        }
        hst[b * 256 + j] = s0 + s1 + s2 + s3;
    } else if (which == 1) {
        float s0 = b_ic[j], s1 = 0.f, s2 = 0.f, s3 = 0.f;
        for (int c = 0; c < 512; c += 4) {
            s0 += pc[((size_t)((c + 0) * 32 + b)) * 256 + j];
            s1 += pc[((size_t)((c + 1) * 32 + b)) * 256 + j];
            s2 += pc[((size_t)((c + 2) * 32 + b)) * 256 + j];
            s3 += pc[((size_t)((c + 3) * 32 + b)) * 256 + j];
        }
        cst[b * 256 + j] = s0 + s1 + s2 + s3;
    } else {
        float s0 = b_iC[j], s1 = 0.f, s2 = 0.f, s3 = 0.f;
        for (int c = 0; c < 128; c += 4) {
            s0 += pC[((size_t)((c + 0) * 32 + b)) * 256 + j];
            s1 += pC[((size_t)((c + 1) * 32 + b)) * 256 + j];
            s2 += pC[((size_t)((c + 2) * 32 + b)) * 256 + j];
            s3 += pC[((size_t)((c + 3) * 32 + b)) * 256 + j];
        }
        Cst[b * 256 + j] = s0 + s1 + s2 + s3;
    }
}

// ---------------- init: at2p slot0 = h0 @ W_dec (no bias), zero rest + awf ----------------
__global__ __launch_bounds__(256) void k_init2(const float* __restrict__ hst, const float* __restrict__ W_dec,
                                               float* __restrict__ at2p, float* __restrict__ awf) {
    __shared__ __align__(16) float hs[8192];
    int tid = threadIdx.x;
    for (int i = blockIdx.x * 256 + tid; i < 8192; i += 1024) awf[i] = 0.f;
    for (int i = tid; i < 2048; i += 256) ((float4*)hs)[i] = ((const float4*)hst)[i];
    __syncthreads();
    int col = blockIdx.x * 64 + (tid & 63), bg = tid >> 6;
    float acc[8] = {0.f,0.f,0.f,0.f,0.f,0.f,0.f,0.f};
    for (int k = 0; k < 256; ++k) {
        float w = W_dec[(size_t)k * 256 + col];
#pragma unroll
        for (int bi = 0; bi < 8; ++bi) acc[bi] += hs[(bg * 8 + bi) * 256 + k] * w;
    }
#pragma unroll
    for (int bi = 0; bi < 8; ++bi) {
        int b = bg * 8 + bi;
        at2p[((size_t)(b * 8 + 0)) * 256 + col] = acc[bi];
#pragma unroll
        for (int ct = 1; ct < 8; ++ct) at2p[((size_t)(b * 8 + ct)) * 256 + col] = 0.f;
    }
}

// ---------------- att1 = info_sorted @ W_enc + b_enc ----------------
__global__ __launch_bounds__(256) void k_att1(const float* __restrict__ info, const int* __restrict__ ord,
                                              const float* __restrict__ W, const float* __restrict__ bias,
                                              float* __restrict__ att1) {
    __shared__ __align__(16) float xsT[256 * 36];
    int tid = threadIdx.x;
    int r0 = blockIdx.x * 32;
    int b = r0 >> 10, p0 = r0 & 1023;
    const float* src = info + (size_t)ord[b] * INFLAT + (size_t)p0 * 256;
    for (int idx = tid; idx < 2048; idx += 256) {
        int r = idx >> 6, kq = idx & 63;
        float4 v = *(const float4*)&src[r * 256 + kq * 4];
        xsT[(kq * 4 + 0) * 36 + r] = v.x;
        xsT[(kq * 4 + 1) * 36 + r] = v.y;
        xsT[(kq * 4 + 2) * 36 + r] = v.z;
        xsT[(kq * 4 + 3) * 36 + r] = v.w;
    }
    __syncthreads();
    float acc[32];
#pragma unroll
    for (int r = 0; r < 32; ++r) acc[r] = 0.f;
    for (int k = 0; k < 256; ++k) {
        float w = W[k * 256 + tid];
        const float4* xr = (const float4*)&xsT[k * 36];
#pragma unroll
        for (int rq = 0; rq < 8; ++rq) {
            float4 x4 = xr[rq];
            acc[rq * 4 + 0] += x4.x * w;
            acc[rq * 4 + 1] += x4.y * w;
            acc[rq * 4 + 2] += x4.z * w;
            acc[rq * 4 + 3] += x4.w * w;
        }
    }
    float bj = bias[tid];
#pragma unroll
    for (int r = 0; r < 32; ++r) att1[((size_t)(r0 + r)) * 256 + tid] = acc[r] + bj;
}

// ---------------- fused steps kernel ----------------
struct KArgs {
    const float *info, *emb, *W_dec, *b_dec, *W_full, *b_full;
    const float *W_i, *W_f, *W_o, *W_g1, *W_g2;
    const float *b_i, *b_f, *b_o, *b_g1, *b_g2;
    const float *W_mlp, *b_mlp, *W_fc, *b_fc;
    const int *caps;
    float *att1, *expe, *zpart, *awf, *gsp, *hst, *cst0, *Cst0, *cst1, *Cst1, *at2p;
    const int *ord, *slp;
    int *root, *slots;
    float *out_pred, *out_alpha;
};

__device__ void pred_task2(const KArgs& a, float* sm, int tile, int tm1) {
    int tid = threadIdx.x;
    for (int i = tid; i < 8192; i += 256) sm[i] = agload(&a.hst[i]);
    __syncthreads();
    int col = tile * 64 + (tid & 63), bg = tid >> 6;
    if (col >= Vz) return;
    float acc[8] = {0.f, 0.f, 0.f, 0.f, 0.f, 0.f, 0.f, 0.f};
    for (int jq = 0; jq < 64; ++jq) {
        float w0 = a.W_fc[(size_t)(jq * 4 + 0) * Vz + col];
        float w1 = a.W_fc[(size_t)(jq * 4 + 1) * Vz + col];
        float w2 = a.W_fc[(size_t)(jq * 4 + 2) * Vz + col];
        float w3 = a.W_fc[(size_t)(jq * 4 + 3) * Vz + col];
#pragma unroll
        for (int bi = 0; bi < 8; ++bi) {
            float4 h4 = *(const float4*)&sm[(bg * 8 + bi) * 256 + jq * 4];
            acc[bi] += h4.x * w0 + h4.y * w1 + h4.z * w2 + h4.w * w3;
        }
    }
    float bv = a.b_fc[col];
#pragma unroll
    for (int bi = 0; bi < 8; ++bi) {
        int b = bg * 8 + bi;
        float r = (a.slp[b] > tm1) ? (acc[bi] + bv) : 0.f;
        a.out_pred[((size_t)b * TMz + tm1) * Vz + col] = r;
    }
}

// LDS: PA: [256..511] at2, [512..767] wf, [768..1023] epart, [1024..1087] ex
// PB gates: [0..8191] x-stage, [8192..8223] invZ; pred: [0..8191] h
// PC: [0..255] nc, [256..511] nC, [512..767] ov, [768..1055] mred, [1056..1087] hsl
__global__ __launch_bounds__(256, 2) void k_steps(KArgs a) {
    __shared__ __align__(16) float sm[8224];
    __shared__ int caps_s[32];
    int bid = blockIdx.x, tid = threadIdx.x;
    int b = bid >> 4, sub = bid & 15;
    int gen = 0;

    for (int t = 0; t < TMz; ++t) {
        // ---------- PA: at2 (from partials) + e + expe + zpart + awf (512 blocks) ----------
        {
            float v = a.b_dec[tid];
#pragma unroll
            for (int ct = 0; ct < 8; ++ct) v += agload(&a.at2p[((size_t)(b * 8 + ct)) * 256 + tid]);
            sm[256 + tid] = v;
            sm[512 + tid] = a.W_full[tid];
            __syncthreads();
            int pl = tid & 63, kq = tid >> 6;
            const float* row = a.att1 + ((size_t)(b * 1024 + sub * 64 + pl)) * 256 + kq * 64;
            const float* a2 = sm + 256 + kq * 64;
            const float* wf = sm + 512 + kq * 64;
            float part = 0.f;
#pragma unroll
            for (int q = 0; q < 16; ++q) {
                float4 r4 = *(const float4*)&row[q * 4];
                part += fmaxf(r4.x + a2[q * 4 + 0], 0.f) * wf[q * 4 + 0]
                      + fmaxf(r4.y + a2[q * 4 + 1], 0.f) * wf[q * 4 + 1]
                      + fmaxf(r4.z + a2[q * 4 + 2], 0.f) * wf[q * 4 + 2]
                      + fmaxf(r4.w + a2[q * 4 + 3], 0.f) * wf[q * 4 + 3];
            }
            sm[768 + kq * 64 + pl] = part;
            __syncthreads();
            if (tid < 64) {
                float e = sm[768 + tid] + sm[832 + tid] + sm[896 + tid] + sm[960 + tid] + a.b_full[0];
                float ex = expf(e);
                agstore(&a.expe[b * 1024 + sub * 64 + tid], ex);
                sm[1024 + tid] = ex;
                float s = ex;
                s += __shfl_down(s, 32); s += __shfl_down(s, 16); s += __shfl_down(s, 8);
                s += __shfl_down(s, 4);  s += __shfl_down(s, 2);  s += __shfl_down(s, 1);
                if (tid == 0) agstore(&a.zpart[b * 16 + sub], s);
            }
            __syncthreads();
            const float* ib = a.info + (size_t)a.ord[b] * INFLAT + (size_t)(sub * 64) * 256;
            const float* ex = sm + 1024;
            float q0=0.f,q1=0.f,q2=0.f,q3=0.f,q4=0.f,q5=0.f,q6=0.f,q7=0.f;
            for (int i = 0; i < 64; i += 8) {
                q0 += ex[i+0] * ib[(size_t)(i+0) * 256 + tid];
                q1 += ex[i+1] * ib[(size_t)(i+1) * 256 + tid];
                q2 += ex[i+2] * ib[(size_t)(i+2) * 256 + tid];
                q3 += ex[i+3] * ib[(size_t)(i+3) * 256 + tid];
                q4 += ex[i+4] * ib[(size_t)(i+4) * 256 + tid];
                q5 += ex[i+5] * ib[(size_t)(i+5) * 256 + tid];
                q6 += ex[i+6] * ib[(size_t)(i+6) * 256 + tid];
                q7 += ex[i+7] * ib[(size_t)(i+7) * 256 + tid];
            }
            agadd(&a.awf[b * 256 + tid], ((q0+q1)+(q2+q3)) + ((q4+q5)+(q6+q7)));
        }
        gbar(a.slots, a.root, ++gen);

        // ---------- PB: gates(0..79) | alpha(80..111) | pred(112..268) ----------
        if (bid < 80) {
            int g = bid / 16, s16 = bid % 16;
            int ct = s16 >> 2, kc = s16 & 3;
            const float* Wg  = (g == 0) ? a.W_i : (g == 1) ? a.W_f : (g == 2) ? a.W_o : (g == 3) ? a.W_g1 : a.W_g2;
            if (kc == 2 && tid < 32) {
                float Z = 0.f;
#pragma unroll
                for (int c = 0; c < 16; ++c) Z += agload(&a.zpart[tid * 16 + c]);
                sm[8192 + tid] = 1.0f / Z;
            }
            if (kc < 2 && tid >= 64 && tid < 96) caps_s[tid - 64] = a.caps[a.ord[tid - 64] * Tz + t];
            __syncthreads();
            for (int idx = tid; idx < 8192; idx += 256) {
                int b2 = idx >> 8, kk = idx & 255;
                float v;
                if (kc == 0)      v = a.emb[(size_t)caps_s[b2] * 512 + kk];
                else if (kc == 1) v = a.emb[(size_t)caps_s[b2] * 512 + 256 + kk];
                else if (kc == 2) v = agload(&a.awf[b2 * 256 + kk]) * sm[8192 + b2];
                else              v = agload(&a.hst[b2 * 256 + kk]);
                sm[idx] = v;
            }
            __syncthreads();
            int col = ct * 64 + (tid & 63), bg = tid >> 6;
            float acc[8] = {0.f,0.f,0.f,0.f,0.f,0.f,0.f,0.f};
            int wbase = kc * 256;
            for (int kk = 0; kk < 256; kk += 4) {
                float w0 = Wg[(size_t)(wbase + kk + 0) * 256 + col];
                float w1 = Wg[(size_t)(wbase + kk + 1) * 256 + col];
                float w2 = Wg[(size_t)(wbase + kk + 2) * 256 + col];
                float w3 = Wg[(size_t)(wbase + kk + 3) * 256 + col];
#pragma unroll
                for (int bi = 0; bi < 8; ++bi) {
                    float4 x4 = *(const float4*)&sm[(bg * 8 + bi) * 256 + kk];
                    acc[bi] += x4.x * w0 + x4.y * w1 + x4.z * w2 + x4.w * w3;
                }
            }
#pragma unroll
            for (int bi = 0; bi < 8; ++bi)
                agstore(&a.gsp[((size_t)((g * 4 + kc) * 32 + bg * 8 + bi)) * 256 + col], acc[bi]);
        } else if (bid < 112) {
            int bb = bid - 80;
            float Z = 0.f;
#pragma unroll
            for (int c = 0; c < 16; ++c) Z += agload(&a.zpart[bb * 16 + c]);
            float invZ = 1.0f / Z;
            float am = (a.slp[bb] > t) ? invZ : 0.f;
            float* oal = a.out_alpha + ((size_t)bb * TMz + t) * 1024;
            for (int p = tid; p < 1024; p += 256) oal[p] = agload(&a.expe[bb * 1024 + p]) * am;
        } else if (t > 0 && bid < 269) {
            pred_task2(a, sm, bid - 112, t - 1);
        }
        gbar(a.slots, a.root, ++gen);

        // ---------- PC: cell + mlp + h + at2p + awf-zero (256 blocks: b x ct8) ----------
        // cst/Cst are ping-pong double-buffered by step parity: readers read buf[t&1],
        // only ct==0 writes buf[(t+1)&1] -> no same-phase read/write race (R8 bug fix).
        if (bid < 256) {
            int bb = bid >> 3, ct = bid & 7;
            int j = tid;
            const float* csOld = (t & 1) ? a.cst1 : a.cst0;
            const float* CsOld = (t & 1) ? a.Cst1 : a.Cst0;
            float* csNew = (t & 1) ? a.cst0 : a.cst1;
            float* CsNew = (t & 1) ? a.Cst0 : a.Cst1;
            float gs[5];
#pragma unroll
            for (int g = 0; g < 5; ++g) {
                float s = 0.f;
#pragma unroll
                for (int kc = 0; kc < 4; ++kc)
                    s += agload(&a.gsp[((size_t)((g * 4 + kc) * 32 + bb)) * 256 + j]);
                gs[g] = s;
            }
            gs[0] += a.b_i[j]; gs[1] += a.b_f[j]; gs[2] += a.b_o[j];
            gs[3] += a.b_g1[j]; gs[4] += a.b_g2[j];
            float iv = sigm(gs[0]), fv = sigm(gs[1]), ov = sigm(gs[2]);
            float g1 = tanhf(gs[3]), g2 = tanhf(gs[4]);
            float nc = fv * agload(&csOld[bb * 256 + j]) + iv * g1;
            float nC = fv * agload(&CsOld[bb * 256 + j]) + iv * g2;
            if (ct == 0) {
                agstore(&csNew[bb * 256 + j], nc);
                agstore(&CsNew[bb * 256 + j], nC);
            }
            sm[j] = nc;
            sm[256 + j] = nC;
            sm[512 + j] = ov;
            __syncthreads();
            // mlp cols ct*32..+31, split-K 8-way
            int colL = tid & 31, kth = tid >> 5;
            int col = ct * 32 + colL;
            float part = 0.f;
            const float* wm = a.W_mlp + col;
            for (int i = 0; i < 64; ++i) {
                int k = kth * 64 + i;
                part += sm[k] * wm[(size_t)k * 256];
            }
            sm[768 + colL * 9 + kth] = part;
            __syncthreads();
            if (tid < 32) {
                int c2 = ct * 32 + tid;
                float m = a.b_mlp[c2];
#pragma unroll
                for (int kk = 0; kk < 8; ++kk) m += sm[768 + tid * 9 + kk];
                float hv = sm[512 + c2] * tanhf(m);
                agstore(&a.hst[bb * 256 + c2], hv);
                sm[1056 + tid] = hv;
                agstore(&a.awf[bb * 256 + c2], 0.f);   // zero awf for next step
            }
            __syncthreads();
            // at2 partial: rank-32 update over this ct's h-slice
            float acc = 0.f;
            const float* wd = a.W_dec + (size_t)(ct * 32) * 256 + tid;
#pragma unroll
            for (int kk = 0; kk < 32; ++kk) acc += sm[1056 + kk] * wd[(size_t)kk * 256];
            agstore(&a.at2p[((size_t)(bb * 8 + ct)) * 256 + tid], acc);
        }
        gbar(a.slots, a.root, ++gen);
    }

    // epilogue: pred for t = 18
    if (bid >= 112 && bid < 269) pred_task2(a, sm, bid - 112, TMz - 1);
}

extern "C" void kernel_launch(void* const* d_in, const int* in_sizes, int n_in,
                              void* d_out, int out_size, void* d_ws, size_t ws_size,
                              hipStream_t stream) {
    const float* info  = (const float*)d_in[0];
    const float* rel   = (const float*)d_in[1];
    const int*   caps  = (const int*)d_in[2];
    const int*   lens  = (const int*)d_in[3];
    const float* emb   = (const float*)d_in[4];
    const float* W_enc = (const float*)d_in[5];
    const float* b_enc = (const float*)d_in[6];
    const float* W_dec = (const float*)d_in[7];
    const float* b_dec = (const float*)d_in[8];
    const float* W_full= (const float*)d_in[9];
    const float* b_full= (const float*)d_in[10];
    const float* W_i   = (const float*)d_in[11];
    const float* b_i   = (const float*)d_in[12];
    const float* W_f   = (const float*)d_in[13];
    const float* b_f   = (const float*)d_in[14];
    const float* W_o   = (const float*)d_in[15];
    const float* b_o   = (const float*)d_in[16];
    const float* W_g1  = (const float*)d_in[17];
    const float* b_g1  = (const float*)d_in[18];
    const float* W_g2  = (const float*)d_in[19];
    const float* b_g2  = (const float*)d_in[20];
    const float* W_mlp = (const float*)d_in[21];
    const float* b_mlp = (const float*)d_in[22];
    const float* W_fc  = (const float*)d_in[25];
    const float* b_fc  = (const float*)d_in[26];
    const float* W_ih  = (const float*)d_in[27];
    const float* b_ih  = (const float*)d_in[28];
    const float* W_ic  = (const float*)d_in[29];
    const float* b_ic  = (const float*)d_in[30];
    const float* W_iC  = (const float*)d_in[31];
    const float* b_iC  = (const float*)d_in[32];

    float* out = (float*)d_out;
    float* out_pred  = out;
    float* out_alpha = out + (size_t)Bz * TMz * Vz;
    float* out_order = out_alpha + (size_t)Bz * TMz * 1024;

    float* w = (float*)d_ws;
    float* ph   = w + WS_PH;
    float* pcp  = w + WS_PC;
    float* att1 = w + WS_ATT1;
    float* expe = w + WS_EXPE;
    float* zpart= w + WS_ZPART;
    float* awf  = w + WS_AWF;
    float* gsp  = w + WS_GSP;
    float* hst  = w + WS_HST;
    float* cst0 = w + WS_CST0;
    float* Cst0 = w + WS_CSTB0;
    float* cst1 = w + WS_CST1;
    float* Cst1 = w + WS_CSTB1;
    float* at2p = w + WS_AT2P;
    int*   ordp = (int*)(w + WS_INTS);
    int*   slp  = ordp + 32;
    int*   barmem = ordp + 64;
    float* pC   = w + WS_PCHC;

    k_sort<<<1, 64, 0, stream>>>(lens, out_order, ordp, slp, barmem);
    k_gemv2<<<512, 256, 0, stream>>>(info, ordp, W_ih, W_ic, ph, pcp);
    k_gemvC<<<128, 256, 0, stream>>>(rel, ordp, W_iC, pC);
    k_reduce3<<<96, 256, 0, stream>>>(ph, pcp, pC, b_ih, b_ic, b_iC, hst, cst0, Cst0);
    k_init2<<<4, 256, 0, stream>>>(hst, W_dec, at2p, awf);
    k_att1<<<1024, 256, 0, stream>>>(info, ordp, W_enc, b_enc, att1);

    KArgs ka;
    ka.info = info; ka.emb = emb; ka.W_dec = W_dec; ka.b_dec = b_dec;
    ka.W_full = W_full; ka.b_full = b_full;
    ka.W_i = W_i; ka.W_f = W_f; ka.W_o = W_o; ka.W_g1 = W_g1; ka.W_g2 = W_g2;
    ka.b_i = b_i; ka.b_f = b_f; ka.b_o = b_o; ka.b_g1 = b_g1; ka.b_g2 = b_g2;
    ka.W_mlp = W_mlp; ka.b_mlp = b_mlp; ka.W_fc = W_fc; ka.b_fc = b_fc;
    ka.caps = caps;
    ka.att1 = att1; ka.expe = expe; ka.zpart = zpart; ka.awf = awf;
    ka.gsp = gsp; ka.hst = hst;
    ka.cst0 = cst0; ka.Cst0 = Cst0; ka.cst1 = cst1; ka.Cst1 = Cst1;
    ka.at2p = at2p;
    ka.ord = ordp; ka.slp = slp;
    ka.root = barmem; ka.slots = barmem + 64;
    ka.out_pred = out_pred; ka.out_alpha = out_alpha;

    k_steps<<<NBLK, 256, 0, stream>>>(ka);
}

// Round 10
// 2294.783 us; speedup vs baseline: 1.8513x; 1.0881x over previous
//
#include <hip/hip_runtime.h>
#include <math.h>

#define Bz 32
#define Tz 20
#define TMz 19
#define Vz 10000
#define INFLAT 262144   // P*D
#define RELSZ 16384
#define NBLK 512

// workspace float offsets
#define WS_PH     0
#define WS_PC     4194304
#define WS_ATT1H  0              // bf16[32*1024*256] = 4.2M floats (reuses ph after k_reduce3)
#define WS_INFOH  4194304        // bf16[32*1024*256] (reuses pc after k_reduce3)
#define WS_EXPE   8388608        // 32768
#define WS_ZPART  8421376        // 512
#define WS_AWF    8421888        // 8192 (atomic-accumulated, unnormalized)
#define WS_GSP    8430080        // 5*4*32*256 = 163840
#define WS_HST    8593920        // 8192
#define WS_CST0   8602112        // 8192
#define WS_CSTB0  8610304        // 8192
#define WS_CST1   8618496        // 8192
#define WS_CSTB1  8626688        // 8192
#define WS_AT2P   8634880        // 8*32*256 = 65536
#define WS_INTS   8700416        // ordp[32] slp[32] barmem[64+512]
#define WS_PCHC   8701440        // 128*32*256 = 1048576

__device__ __forceinline__ float sigm(float x) { return 1.0f / (1.0f + expf(-x)); }

__device__ __forceinline__ unsigned short f2bf(float f) {
    unsigned int x = __float_as_uint(f);
    unsigned int r = (x + 0x7fffu + ((x >> 16) & 1u)) >> 16;
    return (unsigned short)r;
}

// Agent-scope accessors for cross-block-communicated state ONLY.
__device__ __forceinline__ float agload(const float* p) {
    return __hip_atomic_load(p, __ATOMIC_RELAXED, __HIP_MEMORY_SCOPE_AGENT);
}
__device__ __forceinline__ void agstore(float* p, float v) {
    __hip_atomic_store(p, v, __ATOMIC_RELAXED, __HIP_MEMORY_SCOPE_AGENT);
}
__device__ __forceinline__ int agloadi(const int* p) {
    return __hip_atomic_load(p, __ATOMIC_RELAXED, __HIP_MEMORY_SCOPE_AGENT);
}
__device__ __forceinline__ void agstorei(int* p, int v) {
    __hip_atomic_store(p, v, __ATOMIC_RELAXED, __HIP_MEMORY_SCOPE_AGENT);
}
__device__ __forceinline__ void agadd(float* p, float v) {
    __hip_atomic_fetch_add(p, v, __ATOMIC_RELAXED, __HIP_MEMORY_SCOPE_AGENT);
}

__device__ __forceinline__ void gl_lds16(const float* g, float* l) {
    __builtin_amdgcn_global_load_lds(
        (const __attribute__((address_space(1))) unsigned int*)g,
        (__attribute__((address_space(3))) unsigned int*)l,
        16, 0, 0);
}

// Fence-free slot grid barrier (no cache invalidation).
__device__ __forceinline__ void gbar(int* slots, int* root, int gen) {
    asm volatile("s_waitcnt vmcnt(0)" ::: "memory");
    __syncthreads();
    if (blockIdx.x == 0) {
        int i0 = threadIdx.x, i1 = threadIdx.x + 256;
        if (i0 != 0) {
            while (agloadi(&slots[i0]) < gen) __builtin_amdgcn_s_sleep(1);
        }
        while (agloadi(&slots[i1]) < gen) __builtin_amdgcn_s_sleep(1);
        __syncthreads();
        if (threadIdx.x == 0) agstorei(root, gen);
    } else if (threadIdx.x == 0) {
        agstorei(&slots[blockIdx.x], gen);
        while (agloadi(root) < gen) __builtin_amdgcn_s_sleep(2);
    }
    __syncthreads();
    asm volatile("" ::: "memory");
}

// ---------------- sort + barrier init ----------------
__global__ void k_sort(const int* __restrict__ lens, float* __restrict__ out_order,
                       int* __restrict__ ord, int* __restrict__ sentlen, int* __restrict__ barmem) {
    if (threadIdx.x == 0 && blockIdx.x == 0) {
        for (int i = 0; i < 64 + NBLK; ++i) barmem[i] = 0;
        int l[Bz]; bool used[Bz];
        for (int b = 0; b < Bz; ++b) { l[b] = lens[b]; used[b] = false; }
        for (int i = 0; i < Bz; ++i) {
            int best = -1;
            for (int j = 0; j < Bz; ++j)
                if (!used[j] && (best < 0 || l[j] > l[best])) best = j;
            used[best] = true;
            ord[i] = best;
            sentlen[i] = l[best] - 1;
            out_order[i] = (float)best;
        }
    }
}

// ---------------- h0,c0: flat(32,262144) @ W_ih / W_ic ----------------
__global__ __launch_bounds__(256) void k_gemv2(const float* __restrict__ X, const int* __restrict__ ord,
                                               const float* __restrict__ W1, const float* __restrict__ W2,
                                               float* __restrict__ p1, float* __restrict__ p2) {
    __shared__ __align__(16) float wlds[8192];
    __shared__ __align__(16) float xsT[256 * 36];
    __shared__ int ords[32];
    int tid = threadIdx.x;
    int wv = tid >> 6, ln = tid & 63;
    size_t k0 = (size_t)blockIdx.x * 512;

    if (tid < 32) ords[tid] = ord[tid];
    __syncthreads();

    auto stage_xs = [&](int hh) {
        for (int idx = tid; idx < 2048; idx += 256) {
            int b = idx >> 6, kq = idx & 63;
            float4 v = *(const float4*)&X[(size_t)ords[b] * INFLAT + k0 + (size_t)hh * 256 + kq * 4];
            xsT[(kq * 4 + 0) * 36 + b] = v.x;
            xsT[(kq * 4 + 1) * 36 + b] = v.y;
            xsT[(kq * 4 + 2) * 36 + b] = v.z;
            xsT[(kq * 4 + 3) * 36 + b] = v.w;
        }
    };
    auto issue = [&](int n) {
        int slot = n & 1;
        size_t krow = k0 + (size_t)n * 8 + wv * 2;
        const float* g1 = W1 + krow * 256 + ln * 4;
        const float* g2 = W2 + krow * 256 + ln * 4;
        float* l1 = &wlds[slot * 4096 + (wv * 2) * 256 + ln * 4];
        float* l2 = &wlds[slot * 4096 + 2048 + (wv * 2) * 256 + ln * 4];
        gl_lds16(g1, l1);
        gl_lds16(g2, l2);
        gl_lds16(g1 + 256, l1 + 256);
        gl_lds16(g2 + 256, l2 + 256);
    };

    float ah[32], ac[32];
#pragma unroll
    for (int b = 0; b < 32; ++b) { ah[b] = 0.f; ac[b] = 0.f; }

    stage_xs(0);
    issue(0);

#pragma unroll 1
    for (int c = 0; c < 64; ++c) {
        if (c == 32) stage_xs(1);
        if (c + 1 < 64) {
            issue(c + 1);
            asm volatile("s_waitcnt vmcnt(4)" ::: "memory");
        } else {
            asm volatile("s_waitcnt vmcnt(0)" ::: "memory");
        }
        __syncthreads();
        int slot = c & 1;
        int xb0 = (c & 31) * 8;
#pragma unroll
        for (int kk = 0; kk < 8; ++kk) {
            float w1 = wlds[slot * 4096 + kk * 256 + tid];
            float w2 = wlds[slot * 4096 + 2048 + kk * 256 + tid];
            const float4* xr = (const float4*)&xsT[(xb0 + kk) * 36];
#pragma unroll
            for (int bq = 0; bq < 8; ++bq) {
                float4 x4 = xr[bq];
                ah[bq * 4 + 0] += x4.x * w1; ac[bq * 4 + 0] += x4.x * w2;
                ah[bq * 4 + 1] += x4.y * w1; ac[bq * 4 + 1] += x4.y * w2;
                ah[bq * 4 + 2] += x4.z * w1; ac[bq * 4 + 2] += x4.z * w2;
                ah[bq * 4 + 3] += x4.w * w1; ac[bq * 4 + 3] += x4.w * w2;
            }
        }
        __syncthreads();
    }
#pragma unroll
    for (int b = 0; b < 32; ++b) {
        size_t o = ((size_t)blockIdx.x * 32 + b) * 256 + tid;
        p1[o] = ah[b];
        p2[o] = ac[b];
    }
}

// ---------------- C0: rel(32,16384) @ W_iC, split-K ----------------
__global__ __launch_bounds__(256) void k_gemvC(const float* __restrict__ R, const int* __restrict__ ord,
                                               const float* __restrict__ W, float* __restrict__ p) {
    __shared__ float xs[32 * 128];
    __shared__ int ords[32];
    int tid = threadIdx.x, bx = blockIdx.x;
    if (tid < 32) ords[tid] = ord[tid];
    __syncthreads();
    int k0 = bx * 128;
    for (int idx = tid; idx < 32 * 128; idx += 256) {
        int b = idx >> 7, kk = idx & 127;
        xs[idx] = R[(size_t)ords[b] * RELSZ + k0 + kk];
    }
    __syncthreads();
    float acc[32];
#pragma unroll
    for (int b = 0; b < 32; ++b) acc[b] = 0.f;
    for (int kk = 0; kk < 128; ++kk) {
        float w = W[(size_t)(k0 + kk) * 256 + tid];
#pragma unroll
        for (int b = 0; b < 32; ++b) acc[b] += xs[b * 128 + kk] * w;
    }
#pragma unroll
    for (int b = 0; b < 32; ++b) p[((size_t)bx * 32 + b) * 256 + tid] = acc[b];
}

// ---------------- combined split-K reduces: h0, c0, C0 ----------------
__global__ __launch_bounds__(256) void k_reduce3(const float* __restrict__ ph, const float* __restrict__ pc,
                                                 const float* __restrict__ pC,
                                                 const float* __restrict__ b_ih, const float* __restrict__ b_ic,
                                                 const float* __restrict__ b_iC,
                                                 float* __restrict__ hst, float* __restrict__ cst,
                                                 float* __restrict__ Cst) {
    int which = blockIdx.x >> 5, b = blockIdx.x & 31, j = threadIdx.x;
    if (which == 0) {
        float s0 = b_ih[j], s1 = 0.f, s2 = 0.f, s3 = 0.f;
        for (int c = 0; c < 512; c += 4) {
            s0 += ph[((size_t)((c + 0) * 32 + b)) * 256 + j];
            s1 += ph[((size_t)((c + 1) * 32 + b)) * 256 + j];
            s2 += ph[((size_t)((c + 2) * 32 + b)) * 256 + j];
            s3 += ph[((size_t)((c + 3) * 32 + b)) * 256 + j];
        }
        hst[b * 256 + j] = s0 + s1 + s2 + s3;
    } else if (which == 1) {
        float s0 = b_ic[j], s1 = 0.f, s2 = 0.f, s3 = 0.f;
        for (int c = 0; c < 512; c += 4) {
            s0 += pc[((size_t)((c + 0) * 32 + b)) * 256 + j];
            s1 += pc[((size_t)((c + 1) * 32 + b)) * 256 + j];
            s2 += pc[((size_t)((c + 2) * 32 + b)) * 256 + j];
            s3 += pc[((size_t)((c + 3) * 32 + b)) * 256 + j];
        }
        cst[b * 256 + j] = s0 + s1 + s2 + s3;
    } else {
        float s0 = b_iC[j], s1 = 0.f, s2 = 0.f, s3 = 0.f;
        for (int c = 0; c < 128; c += 4) {
            s0 += pC[((size_t)((c + 0) * 32 + b)) * 256 + j];
            s1 += pC[((size_t)((c + 1) * 32 + b)) * 256 + j];
            s2 += pC[((size_t)((c + 2) * 32 + b)) * 256 + j];
            s3 += pC[((size_t)((c + 3) * 32 + b)) * 256 + j];
        }
        Cst[b * 256 + j] = s0 + s1 + s2 + s3;
    }
}

// ---------------- init: at2p slot0 = h0 @ W_dec (no bias), zero rest + awf ----------------
__global__ __launch_bounds__(256) void k_init2(const float* __restrict__ hst, const float* __restrict__ W_dec,
                                               float* __restrict__ at2p, float* __restrict__ awf) {
    __shared__ __align__(16) float hs[8192];
    int tid = threadIdx.x;
    for (int i = blockIdx.x * 256 + tid; i < 8192; i += 1024) awf[i] = 0.f;
    for (int i = tid; i < 2048; i += 256) ((float4*)hs)[i] = ((const float4*)hst)[i];
    __syncthreads();
    int col = blockIdx.x * 64 + (tid & 63), bg = tid >> 6;
    float acc[8] = {0.f,0.f,0.f,0.f,0.f,0.f,0.f,0.f};
    for (int k = 0; k < 256; ++k) {
        float w = W_dec[(size_t)k * 256 + col];
#pragma unroll
        for (int bi = 0; bi < 8; ++bi) acc[bi] += hs[(bg * 8 + bi) * 256 + k] * w;
    }
#pragma unroll
    for (int bi = 0; bi < 8; ++bi) {
        int b = bg * 8 + bi;
        at2p[((size_t)(b * 8 + 0)) * 256 + col] = acc[bi];
#pragma unroll
        for (int ct = 1; ct < 8; ++ct) at2p[((size_t)(b * 8 + ct)) * 256 + col] = 0.f;
    }
}

// ---------------- att1h = bf16(info_sorted @ W_enc + b_enc); infoh = bf16(info_sorted) ----------------
__global__ __launch_bounds__(256) void k_att1(const float* __restrict__ info, const int* __restrict__ ord,
                                              const float* __restrict__ W, const float* __restrict__ bias,
                                              unsigned short* __restrict__ att1h,
                                              unsigned short* __restrict__ infoh) {
    __shared__ __align__(16) float xsT[256 * 36];
    int tid = threadIdx.x;
    int r0 = blockIdx.x * 32;
    int b = r0 >> 10, p0 = r0 & 1023;
    const float* src = info + (size_t)ord[b] * INFLAT + (size_t)p0 * 256;
    for (int idx = tid; idx < 2048; idx += 256) {
        int r = idx >> 6, kq = idx & 63;
        float4 v = *(const float4*)&src[r * 256 + kq * 4];
        xsT[(kq * 4 + 0) * 36 + r] = v.x;
        xsT[(kq * 4 + 1) * 36 + r] = v.y;
        xsT[(kq * 4 + 2) * 36 + r] = v.z;
        xsT[(kq * 4 + 3) * 36 + r] = v.w;
    }
    __syncthreads();
    // bf16 copy of this info tile (thread tid = col tid, rows r0..r0+31)
#pragma unroll 4
    for (int r = 0; r < 32; ++r)
        infoh[(size_t)(r0 + r) * 256 + tid] = f2bf(xsT[tid * 36 + r]);
    float acc[32];
#pragma unroll
    for (int r = 0; r < 32; ++r) acc[r] = 0.f;
    for (int k = 0; k < 256; ++k) {
        float w = W[k * 256 + tid];
        const float4* xr = (const float4*)&xsT[k * 36];
#pragma unroll
        for (int rq = 0; rq < 8; ++rq) {
            float4 x4 = xr[rq];
            acc[rq * 4 + 0] += x4.x * w;
            acc[rq * 4 + 1] += x4.y * w;
            acc[rq * 4 + 2] += x4.z * w;
            acc[rq * 4 + 3] += x4.w * w;
        }
    }
    float bj = bias[tid];
#pragma unroll
    for (int r = 0; r < 32; ++r)
        att1h[(size_t)(r0 + r) * 256 + tid] = f2bf(acc[r] + bj);
}

// ---------------- fused steps kernel ----------------
struct KArgs {
    const float *info, *emb, *W_dec, *b_dec, *W_full, *b_full;
    const float *W_i, *W_f, *W_o, *W_g1, *W_g2;
    const float *b_i, *b_f, *b_o, *b_g1, *b_g2;
    const float *W_mlp, *b_mlp, *W_fc, *b_fc;
    const int *caps;
    const unsigned short *att1h, *infoh;
    float *expe, *zpart, *awf, *gsp, *hst, *cst0, *Cst0, *cst1, *Cst1, *at2p;
    const int *ord, *slp;
    int *root, *slots;
    float *out_pred, *out_alpha;
};

__device__ void pred_task2(const KArgs& a, float* sm, int tile, int tm1) {
    int tid = threadIdx.x;
    for (int i = tid; i < 8192; i += 256) sm[i] = agload(&a.hst[i]);
    __syncthreads();
    int col = tile * 64 + (tid & 63), bg = tid >> 6;
    if (col >= Vz) return;
    float acc[8] = {0.f, 0.f, 0.f, 0.f, 0.f, 0.f, 0.f, 0.f};
    for (int jq = 0; jq < 64; ++jq) {
        float w0 = a.W_fc[(size_t)(jq * 4 + 0) * Vz + col];
        float w1 = a.W_fc[(size_t)(jq * 4 + 1) * Vz + col];
        float w2 = a.W_fc[(size_t)(jq * 4 + 2) * Vz + col];
        float w3 = a.W_fc[(size_t)(jq * 4 + 3) * Vz + col];
#pragma unroll
        for (int bi = 0; bi < 8; ++bi) {
            float4 h4 = *(const float4*)&sm[(bg * 8 + bi) * 256 + jq * 4];
            acc[bi] += h4.x * w0 + h4.y * w1 + h4.z * w2 + h4.w * w3;
        }
    }
    float bv = a.b_fc[col];
#pragma unroll
    for (int bi = 0; bi < 8; ++bi) {
        int b = bg * 8 + bi;
        float r = (a.slp[b] > tm1) ? (acc[bi] + bv) : 0.f;
        a.out_pred[((size_t)b * TMz + tm1) * Vz + col] = r;
    }
}

// LDS: PA: [256..511] at2, [512..767] wf, [768..1023] epart, [1024..1087] ex, [1088..1599] awf-part
// PB gates: [0..8191] x-stage, [8192..8223] invZ; pred: [0..8191] h
// PC: [0..255] nc, [256..511] nC, [512..767] ov, [768..1055] mred, [1056..1087] hsl
__global__ __launch_bounds__(256, 2) void k_steps(KArgs a) {
    __shared__ __align__(16) float sm[8224];
    __shared__ int caps_s[32];
    int bid = blockIdx.x, tid = threadIdx.x;
    int b = bid >> 4, sub = bid & 15;
    int gen = 0;

    for (int t = 0; t < TMz; ++t) {
        // ---------- PA: at2 (from partials) + e + expe + zpart + awf (512 blocks) ----------
        {
            float v = a.b_dec[tid];
#pragma unroll
            for (int ct = 0; ct < 8; ++ct) v += agload(&a.at2p[((size_t)(b * 8 + ct)) * 256 + tid]);
            sm[256 + tid] = v;
            sm[512 + tid] = a.W_full[tid];
            __syncthreads();
            int pl = tid & 63, kq = tid >> 6;
            const unsigned short* rowh = a.att1h + ((size_t)(b * 1024 + sub * 64 + pl)) * 256 + kq * 64;
            const float* a2 = sm + 256 + kq * 64;
            const float* wf = sm + 512 + kq * 64;
            float part = 0.f;
#pragma unroll
            for (int q = 0; q < 8; ++q) {
                uint4 u = ((const uint4*)rowh)[q];
                const float* A = a2 + q * 8;
                const float* W = wf + q * 8;
                part += fmaxf(__uint_as_float(u.x << 16)         + A[0], 0.f) * W[0];
                part += fmaxf(__uint_as_float(u.x & 0xffff0000u) + A[1], 0.f) * W[1];
                part += fmaxf(__uint_as_float(u.y << 16)         + A[2], 0.f) * W[2];
                part += fmaxf(__uint_as_float(u.y & 0xffff0000u) + A[3], 0.f) * W[3];
                part += fmaxf(__uint_as_float(u.z << 16)         + A[4], 0.f) * W[4];
                part += fmaxf(__uint_as_float(u.z & 0xffff0000u) + A[5], 0.f) * W[5];
                part += fmaxf(__uint_as_float(u.w << 16)         + A[6], 0.f) * W[6];
                part += fmaxf(__uint_as_float(u.w & 0xffff0000u) + A[7], 0.f) * W[7];
            }
            sm[768 + kq * 64 + pl] = part;
            __syncthreads();
            if (tid < 64) {
                float e = sm[768 + tid] + sm[832 + tid] + sm[896 + tid] + sm[960 + tid] + a.b_full[0];
                float ex = expf(e);
                agstore(&a.expe[b * 1024 + sub * 64 + tid], ex);
                sm[1024 + tid] = ex;
                float s = ex;
                s += __shfl_down(s, 32); s += __shfl_down(s, 16); s += __shfl_down(s, 8);
                s += __shfl_down(s, 4);  s += __shfl_down(s, 2);  s += __shfl_down(s, 1);
                if (tid == 0) agstore(&a.zpart[b * 16 + sub], s);
            }
            __syncthreads();
            // awf partial from bf16 infoh: thread group g=tid>>7 covers rows (2i+g), cols (tid&127)*2..+1
            int gg = tid >> 7, c2 = (tid & 127) * 2;
            const unsigned short* ibh = a.infoh + ((size_t)(b * 1024 + sub * 64 + gg)) * 256 + c2;
            const float* ex = sm + 1024;
            float a0 = 0.f, a1 = 0.f;
#pragma unroll
            for (int i = 0; i < 32; ++i) {
                unsigned int u = *(const unsigned int*)(ibh + (size_t)i * 512);
                float ev = ex[i * 2 + gg];
                a0 += ev * __uint_as_float(u << 16);
                a1 += ev * __uint_as_float(u & 0xffff0000u);
            }
            sm[1088 + gg * 256 + c2]     = a0;
            sm[1088 + gg * 256 + c2 + 1] = a1;
            __syncthreads();
            agadd(&a.awf[b * 256 + tid], sm[1088 + tid] + sm[1344 + tid]);
        }
        gbar(a.slots, a.root, ++gen);

        // ---------- PB: gates(0..79) | alpha(80..111) | pred(112..268) ----------
        if (bid < 80) {
            int g = bid / 16, s16 = bid % 16;
            int ct = s16 >> 2, kc = s16 & 3;
            const float* Wg  = (g == 0) ? a.W_i : (g == 1) ? a.W_f : (g == 2) ? a.W_o : (g == 3) ? a.W_g1 : a.W_g2;
            if (kc == 2 && tid < 32) {
                float Z = 0.f;
#pragma unroll
                for (int c = 0; c < 16; ++c) Z += agload(&a.zpart[tid * 16 + c]);
                sm[8192 + tid] = 1.0f / Z;
            }
            if (kc < 2 && tid >= 64 && tid < 96) caps_s[tid - 64] = a.caps[a.ord[tid - 64] * Tz + t];
            __syncthreads();
            for (int idx = tid; idx < 8192; idx += 256) {
                int b2 = idx >> 8, kk = idx & 255;
                float v;
                if (kc == 0)      v = a.emb[(size_t)caps_s[b2] * 512 + kk];
                else if (kc == 1) v = a.emb[(size_t)caps_s[b2] * 512 + 256 + kk];
                else if (kc == 2) v = agload(&a.awf[b2 * 256 + kk]) * sm[8192 + b2];
                else              v = agload(&a.hst[b2 * 256 + kk]);
                sm[idx] = v;
            }
            __syncthreads();
            int col = ct * 64 + (tid & 63), bg = tid >> 6;
            float acc[8] = {0.f,0.f,0.f,0.f,0.f,0.f,0.f,0.f};
            int wbase = kc * 256;
            for (int kk = 0; kk < 256; kk += 4) {
                float w0 = Wg[(size_t)(wbase + kk + 0) * 256 + col];
                float w1 = Wg[(size_t)(wbase + kk + 1) * 256 + col];
                float w2 = Wg[(size_t)(wbase + kk + 2) * 256 + col];
                float w3 = Wg[(size_t)(wbase + kk + 3) * 256 + col];
#pragma unroll
                for (int bi = 0; bi < 8; ++bi) {
                    float4 x4 = *(const float4*)&sm[(bg * 8 + bi) * 256 + kk];
                    acc[bi] += x4.x * w0 + x4.y * w1 + x4.z * w2 + x4.w * w3;
                }
            }
#pragma unroll
            for (int bi = 0; bi < 8; ++bi)
                agstore(&a.gsp[((size_t)((g * 4 + kc) * 32 + bg * 8 + bi)) * 256 + col], acc[bi]);
        } else if (bid < 112) {
            int bb = bid - 80;
            float Z = 0.f;
#pragma unroll
            for (int c = 0; c < 16; ++c) Z += agload(&a.zpart[bb * 16 + c]);
            float invZ = 1.0f / Z;
            float am = (a.slp[bb] > t) ? invZ : 0.f;
            float* oal = a.out_alpha + ((size_t)bb * TMz + t) * 1024;
            for (int p = tid; p < 1024; p += 256) oal[p] = agload(&a.expe[bb * 1024 + p]) * am;
        } else if (t > 0 && bid < 269) {
            pred_task2(a, sm, bid - 112, t - 1);
        }
        gbar(a.slots, a.root, ++gen);

        // ---------- PC: cell + mlp + h + at2p + awf-zero (256 blocks: b x ct8) ----------
        // cst/Cst ping-pong by step parity (R8 race fix).
        if (bid < 256) {
            int bb = bid >> 3, ct = bid & 7;
            int j = tid;
            const float* csOld = (t & 1) ? a.cst1 : a.cst0;
            const float* CsOld = (t & 1) ? a.Cst1 : a.Cst0;
            float* csNew = (t & 1) ? a.cst0 : a.cst1;
            float* CsNew = (t & 1) ? a.Cst0 : a.Cst1;
            float gs[5];
#pragma unroll
            for (int g = 0; g < 5; ++g) {
                float s = 0.f;
#pragma unroll
                for (int kc = 0; kc < 4; ++kc)
                    s += agload(&a.gsp[((size_t)((g * 4 + kc) * 32 + bb)) * 256 + j]);
                gs[g] = s;
            }
            gs[0] += a.b_i[j]; gs[1] += a.b_f[j]; gs[2] += a.b_o[j];
            gs[3] += a.b_g1[j]; gs[4] += a.b_g2[j];
            float iv = sigm(gs[0]), fv = sigm(gs[1]), ov = sigm(gs[2]);
            float g1 = tanhf(gs[3]), g2 = tanhf(gs[4]);
            float nc = fv * agload(&csOld[bb * 256 + j]) + iv * g1;
            float nC = fv * agload(&CsOld[bb * 256 + j]) + iv * g2;
            if (ct == 0) {
                agstore(&csNew[bb * 256 + j], nc);
                agstore(&CsNew[bb * 256 + j], nC);
            }
            sm[j] = nc;
            sm[256 + j] = nC;
            sm[512 + j] = ov;
            __syncthreads();
            int colL = tid & 31, kth = tid >> 5;
            int col = ct * 32 + colL;
            float part = 0.f;
            const float* wm = a.W_mlp + col;
            for (int i = 0; i < 64; ++i) {
                int k = kth * 64 + i;
                part += sm[k] * wm[(size_t)k * 256];
            }
            sm[768 + colL * 9 + kth] = part;
            __syncthreads();
            if (tid < 32) {
                int c2 = ct * 32 + tid;
                float m = a.b_mlp[c2];
#pragma unroll
                for (int kk = 0; kk < 8; ++kk) m += sm[768 + tid * 9 + kk];
                float hv = sm[512 + c2] * tanhf(m);
                agstore(&a.hst[bb * 256 + c2], hv);
                sm[1056 + tid] = hv;
                agstore(&a.awf[bb * 256 + c2], 0.f);
            }
            __syncthreads();
            float acc = 0.f;
            const float* wd = a.W_dec + (size_t)(ct * 32) * 256 + tid;
#pragma unroll
            for (int kk = 0; kk < 32; ++kk) acc += sm[1056 + kk] * wd[(size_t)kk * 256];
            agstore(&a.at2p[((size_t)(bb * 8 + ct)) * 256 + tid], acc);
        }
        gbar(a.slots, a.root, ++gen);
    }

    // epilogue: pred for t = 18
    if (bid >= 112 && bid < 269) pred_task2(a, sm, bid - 112, TMz - 1);
}

extern "C" void kernel_launch(void* const* d_in, const int* in_sizes, int n_in,
                              void* d_out, int out_size, void* d_ws, size_t ws_size,
                              hipStream_t stream) {
    const float* info  = (const float*)d_in[0];
    const float* rel   = (const float*)d_in[1];
    const int*   caps  = (const int*)d_in[2];
    const int*   lens  = (const int*)d_in[3];
    const float* emb   = (const float*)d_in[4];
    const float* W_enc = (const float*)d_in[5];
    const float* b_enc = (const float*)d_in[6];
    const float* W_dec = (const float*)d_in[7];
    const float* b_dec = (const float*)d_in[8];
    const float* W_full= (const float*)d_in[9];
    const float* b_full= (const float*)d_in[10];
    const float* W_i   = (const float*)d_in[11];
    const float* b_i   = (const float*)d_in[12];
    const float* W_f   = (const float*)d_in[13];
    const float* b_f   = (const float*)d_in[14];
    const float* W_o   = (const float*)d_in[15];
    const float* b_o   = (const float*)d_in[16];
    const float* W_g1  = (const float*)d_in[17];
    const float* b_g1  = (const float*)d_in[18];
    const float* W_g2  = (const float*)d_in[19];
    const float* b_g2  = (const float*)d_in[20];
    const float* W_mlp = (const float*)d_in[21];
    const float* b_mlp = (const float*)d_in[22];
    const float* W_fc  = (const float*)d_in[25];
    const float* b_fc  = (const float*)d_in[26];
    const float* W_ih  = (const float*)d_in[27];
    const float* b_ih  = (const float*)d_in[28];
    const float* W_ic  = (const float*)d_in[29];
    const float* b_ic  = (const float*)d_in[30];
    const float* W_iC  = (const float*)d_in[31];
    const float* b_iC  = (const float*)d_in[32];

    float* out = (float*)d_out;
    float* out_pred  = out;
    float* out_alpha = out + (size_t)Bz * TMz * Vz;
    float* out_order = out_alpha + (size_t)Bz * TMz * 1024;

    float* w = (float*)d_ws;
    float* ph   = w + WS_PH;
    float* pcp  = w + WS_PC;
    unsigned short* att1h = (unsigned short*)(w + WS_ATT1H);
    unsigned short* infoh = (unsigned short*)(w + WS_INFOH);
    float* expe = w + WS_EXPE;
    float* zpart= w + WS_ZPART;
    float* awf  = w + WS_AWF;
    float* gsp  = w + WS_GSP;
    float* hst  = w + WS_HST;
    float* cst0 = w + WS_CST0;
    float* Cst0 = w + WS_CSTB0;
    float* cst1 = w + WS_CST1;
    float* Cst1 = w + WS_CSTB1;
    float* at2p = w + WS_AT2P;
    int*   ordp = (int*)(w + WS_INTS);
    int*   slp  = ordp + 32;
    int*   barmem = ordp + 64;
    float* pC   = w + WS_PCHC;

    k_sort<<<1, 64, 0, stream>>>(lens, out_order, ordp, slp, barmem);
    k_gemv2<<<512, 256, 0, stream>>>(info, ordp, W_ih, W_ic, ph, pcp);
    k_gemvC<<<128, 256, 0, stream>>>(rel, ordp, W_iC, pC);
    k_reduce3<<<96, 256, 0, stream>>>(ph, pcp, pC, b_ih, b_ic, b_iC, hst, cst0, Cst0);
    k_init2<<<4, 256, 0, stream>>>(hst, W_dec, at2p, awf);
    k_att1<<<1024, 256, 0, stream>>>(info, ordp, W_enc, b_enc, att1h, infoh);

    KArgs ka;
    ka.info = info; ka.emb = emb; ka.W_dec = W_dec; ka.b_dec = b_dec;
    ka.W_full = W_full; ka.b_full = b_full;
    ka.W_i = W_i; ka.W_f = W_f; ka.W_o = W_o; ka.W_g1 = W_g1; ka.W_g2 = W_g2;
    ka.b_i = b_i; ka.b_f = b_f; ka.b_o = b_o; ka.b_g1 = b_g1; ka.b_g2 = b_g2;
    ka.W_mlp = W_mlp; ka.b_mlp = b_mlp; ka.W_fc = W_fc; ka.b_fc = b_fc;
    ka.caps = caps;
    ka.att1h = att1h; ka.infoh = infoh;
    ka.expe = expe; ka.zpart = zpart; ka.awf = awf;
    ka.gsp = gsp; ka.hst = hst;
    ka.cst0 = cst0; ka.Cst0 = Cst0; ka.cst1 = cst1; ka.Cst1 = Cst1;
    ka.at2p = at2p;
    ka.ord = ordp; ka.slp = slp;
    ka.root = barmem; ka.slots = barmem + 64;
    ka.out_pred = out_pred; ka.out_alpha = out_alpha;

    k_steps<<<NBLK, 256, 0, stream>>>(ka);
}

// Round 11
// 2182.583 us; speedup vs baseline: 1.9465x; 1.0514x over previous
//
#include <hip/hip_runtime.h>
#include <math.h>

#define Bz 32
#define Tz 20
#define TMz 19
#define Vz 10000
#define INFLAT 262144   // P*D
#define RELSZ 16384
#define NBLK 512

// workspace float offsets
#define WS_PH     0
#define WS_PC     4194304
#define WS_ATT1H  0              // bf16[32*1024*256] (reuses ph after k_reduce3)
#define WS_INFOH  4194304        // bf16[32*1024*256] (reuses pc after k_reduce3)
#define WS_EXPE   8388608        // 32768
#define WS_ZSUM   8421376        // 32 (atomic-accumulated)
#define WS_AWF    8421888        // 8192 (atomic-accumulated, unnormalized)
#define WS_GSP    8430080        // 5*4*32*256 = 163840
#define WS_HST    8593920        // 8192
#define WS_CST0   8602112
#define WS_CSTB0  8610304
#define WS_CST1   8618496
#define WS_CSTB1  8626688
#define WS_AT2P   8634880        // 8*32*256 = 65536
#define WS_INTS   8700416        // ordp[32] slp[32] barmem[64+512]
#define WS_PCHC   8701440        // 128*32*256 = 1048576

__device__ __forceinline__ float sigm(float x) { return 1.0f / (1.0f + expf(-x)); }

__device__ __forceinline__ unsigned short f2bf(float f) {
    unsigned int x = __float_as_uint(f);
    unsigned int r = (x + 0x7fffu + ((x >> 16) & 1u)) >> 16;
    return (unsigned short)r;
}
__device__ __forceinline__ float bfl(unsigned int u) { return __uint_as_float(u << 16); }
__device__ __forceinline__ float bfh(unsigned int u) { return __uint_as_float(u & 0xffff0000u); }

// Agent-scope accessors for cross-block-communicated state ONLY.
__device__ __forceinline__ float agload(const float* p) {
    return __hip_atomic_load(p, __ATOMIC_RELAXED, __HIP_MEMORY_SCOPE_AGENT);
}
__device__ __forceinline__ void agstore(float* p, float v) {
    __hip_atomic_store(p, v, __ATOMIC_RELAXED, __HIP_MEMORY_SCOPE_AGENT);
}
__device__ __forceinline__ int agloadi(const int* p) {
    return __hip_atomic_load(p, __ATOMIC_RELAXED, __HIP_MEMORY_SCOPE_AGENT);
}
__device__ __forceinline__ void agstorei(int* p, int v) {
    __hip_atomic_store(p, v, __ATOMIC_RELAXED, __HIP_MEMORY_SCOPE_AGENT);
}
__device__ __forceinline__ void agadd(float* p, float v) {
    __hip_atomic_fetch_add(p, v, __ATOMIC_RELAXED, __HIP_MEMORY_SCOPE_AGENT);
}

__device__ __forceinline__ void gl_lds16(const float* g, float* l) {
    __builtin_amdgcn_global_load_lds(
        (const __attribute__((address_space(1))) unsigned int*)g,
        (__attribute__((address_space(3))) unsigned int*)l,
        16, 0, 0);
}

// Fence-free slot grid barrier (no cache invalidation).
__device__ __forceinline__ void gbar(int* slots, int* root, int gen) {
    asm volatile("s_waitcnt vmcnt(0)" ::: "memory");
    __syncthreads();
    if (blockIdx.x == 0) {
        int i0 = threadIdx.x, i1 = threadIdx.x + 256;
        if (i0 != 0) {
            while (agloadi(&slots[i0]) < gen) __builtin_amdgcn_s_sleep(1);
        }
        while (agloadi(&slots[i1]) < gen) __builtin_amdgcn_s_sleep(1);
        __syncthreads();
        if (threadIdx.x == 0) agstorei(root, gen);
    } else if (threadIdx.x == 0) {
        agstorei(&slots[blockIdx.x], gen);
        while (agloadi(root) < gen) __builtin_amdgcn_s_sleep(2);
    }
    __syncthreads();
    asm volatile("" ::: "memory");
}

// ---------------- sort + barrier init ----------------
__global__ void k_sort(const int* __restrict__ lens, float* __restrict__ out_order,
                       int* __restrict__ ord, int* __restrict__ sentlen, int* __restrict__ barmem) {
    if (threadIdx.x == 0 && blockIdx.x == 0) {
        for (int i = 0; i < 64 + NBLK; ++i) barmem[i] = 0;
        int l[Bz]; bool used[Bz];
        for (int b = 0; b < Bz; ++b) { l[b] = lens[b]; used[b] = false; }
        for (int i = 0; i < Bz; ++i) {
            int best = -1;
            for (int j = 0; j < Bz; ++j)
                if (!used[j] && (best < 0 || l[j] > l[best])) best = j;
            used[best] = true;
            ord[i] = best;
            sentlen[i] = l[best] - 1;
            out_order[i] = (float)best;
        }
    }
}

// ---------------- h0,c0: flat(32,262144) @ W_ih / W_ic ----------------
__global__ __launch_bounds__(256) void k_gemv2(const float* __restrict__ X, const int* __restrict__ ord,
                                               const float* __restrict__ W1, const float* __restrict__ W2,
                                               float* __restrict__ p1, float* __restrict__ p2) {
    __shared__ __align__(16) float wlds[8192];
    __shared__ __align__(16) float xsT[256 * 36];
    __shared__ int ords[32];
    int tid = threadIdx.x;
    int wv = tid >> 6, ln = tid & 63;
    size_t k0 = (size_t)blockIdx.x * 512;

    if (tid < 32) ords[tid] = ord[tid];
    __syncthreads();

    auto stage_xs = [&](int hh) {
        for (int idx = tid; idx < 2048; idx += 256) {
            int b = idx >> 6, kq = idx & 63;
            float4 v = *(const float4*)&X[(size_t)ords[b] * INFLAT + k0 + (size_t)hh * 256 + kq * 4];
            xsT[(kq * 4 + 0) * 36 + b] = v.x;
            xsT[(kq * 4 + 1) * 36 + b] = v.y;
            xsT[(kq * 4 + 2) * 36 + b] = v.z;
            xsT[(kq * 4 + 3) * 36 + b] = v.w;
        }
    };
    auto issue = [&](int n) {
        int slot = n & 1;
        size_t krow = k0 + (size_t)n * 8 + wv * 2;
        const float* g1 = W1 + krow * 256 + ln * 4;
        const float* g2 = W2 + krow * 256 + ln * 4;
        float* l1 = &wlds[slot * 4096 + (wv * 2) * 256 + ln * 4];
        float* l2 = &wlds[slot * 4096 + 2048 + (wv * 2) * 256 + ln * 4];
        gl_lds16(g1, l1);
        gl_lds16(g2, l2);
        gl_lds16(g1 + 256, l1 + 256);
        gl_lds16(g2 + 256, l2 + 256);
    };

    float ah[32], ac[32];
#pragma unroll
    for (int b = 0; b < 32; ++b) { ah[b] = 0.f; ac[b] = 0.f; }

    stage_xs(0);
    issue(0);

#pragma unroll 1
    for (int c = 0; c < 64; ++c) {
        if (c == 32) stage_xs(1);
        if (c + 1 < 64) {
            issue(c + 1);
            asm volatile("s_waitcnt vmcnt(4)" ::: "memory");
        } else {
            asm volatile("s_waitcnt vmcnt(0)" ::: "memory");
        }
        __syncthreads();
        int slot = c & 1;
        int xb0 = (c & 31) * 8;
#pragma unroll
        for (int kk = 0; kk < 8; ++kk) {
            float w1 = wlds[slot * 4096 + kk * 256 + tid];
            float w2 = wlds[slot * 4096 + 2048 + kk * 256 + tid];
            const float4* xr = (const float4*)&xsT[(xb0 + kk) * 36];
#pragma unroll
            for (int bq = 0; bq < 8; ++bq) {
                float4 x4 = xr[bq];
                ah[bq * 4 + 0] += x4.x * w1; ac[bq * 4 + 0] += x4.x * w2;
                ah[bq * 4 + 1] += x4.y * w1; ac[bq * 4 + 1] += x4.y * w2;
                ah[bq * 4 + 2] += x4.z * w1; ac[bq * 4 + 2] += x4.z * w2;
                ah[bq * 4 + 3] += x4.w * w1; ac[bq * 4 + 3] += x4.w * w2;
            }
        }
        __syncthreads();
    }
#pragma unroll
    for (int b = 0; b < 32; ++b) {
        size_t o = ((size_t)blockIdx.x * 32 + b) * 256 + tid;
        p1[o] = ah[b];
        p2[o] = ac[b];
    }
}

// ---------------- C0: rel(32,16384) @ W_iC, split-K ----------------
__global__ __launch_bounds__(256) void k_gemvC(const float* __restrict__ R, const int* __restrict__ ord,
                                               const float* __restrict__ W, float* __restrict__ p) {
    __shared__ float xs[32 * 128];
    __shared__ int ords[32];
    int tid = threadIdx.x, bx = blockIdx.x;
    if (tid < 32) ords[tid] = ord[tid];
    __syncthreads();
    int k0 = bx * 128;
    for (int idx = tid; idx < 32 * 128; idx += 256) {
        int b = idx >> 7, kk = idx & 127;
        xs[idx] = R[(size_t)ords[b] * RELSZ + k0 + kk];
    }
    __syncthreads();
    float acc[32];
#pragma unroll
    for (int b = 0; b < 32; ++b) acc[b] = 0.f;
    for (int kk = 0; kk < 128; ++kk) {
        float w = W[(size_t)(k0 + kk) * 256 + tid];
#pragma unroll
        for (int b = 0; b < 32; ++b) acc[b] += xs[b * 128 + kk] * w;
    }
#pragma unroll
    for (int b = 0; b < 32; ++b) p[((size_t)bx * 32 + b) * 256 + tid] = acc[b];
}

// ---------------- combined split-K reduces: h0, c0, C0 ----------------
__global__ __launch_bounds__(256) void k_reduce3(const float* __restrict__ ph, const float* __restrict__ pc,
                                                 const float* __restrict__ pC,
                                                 const float* __restrict__ b_ih, const float* __restrict__ b_ic,
                                                 const float* __restrict__ b_iC,
                                                 float* __restrict__ hst, float* __restrict__ cst,
                                                 float* __restrict__ Cst) {
    int which = blockIdx.x >> 5, b = blockIdx.x & 31, j = threadIdx.x;
    if (which == 0) {
        float s0 = b_ih[j], s1 = 0.f, s2 = 0.f, s3 = 0.f;
        for (int c = 0; c < 512; c += 4) {
            s0 += ph[((size_t)((c + 0) * 32 + b)) * 256 + j];
            s1 += ph[((size_t)((c + 1) * 32 + b)) * 256 + j];
            s2 += ph[((size_t)((c + 2) * 32 + b)) * 256 + j];
            s3 += ph[((size_t)((c + 3) * 32 + b)) * 256 + j];
        }
        hst[b * 256 + j] = s0 + s1 + s2 + s3;
    } else if (which == 1) {
        float s0 = b_ic[j], s1 = 0.f, s2 = 0.f, s3 = 0.f;
        for (int c = 0; c < 512; c += 4) {
            s0 += pc[((size_t)((c + 0) * 32 + b)) * 256 + j];
            s1 += pc[((size_t)((c + 1) * 32 + b)) * 256 + j];
            s2 += pc[((size_t)((c + 2) * 32 + b)) * 256 + j];
            s3 += pc[((size_t)((c + 3) * 32 + b)) * 256 + j];
        }
        cst[b * 256 + j] = s0 + s1 + s2 + s3;
    } else {
        float s0 = b_iC[j], s1 = 0.f, s2 = 0.f, s3 = 0.f;
        for (int c = 0; c < 128; c += 4) {
            s0 += pC[((size_t)((c + 0) * 32 + b)) * 256 + j];
            s1 += pC[((size_t)((c + 1) * 32 + b)) * 256 + j];
            s2 += pC[((size_t)((c + 2) * 32 + b)) * 256 + j];
            s3 += pC[((size_t)((c + 3) * 32 + b)) * 256 + j];
        }
        Cst[b * 256 + j] = s0 + s1 + s2 + s3;
    }
}

// ---------------- init: at2p slot0 = h0 @ W_dec (no bias), zero rest + awf + zsum ----------------
__global__ __launch_bounds__(256) void k_init2(const float* __restrict__ hst, const float* __restrict__ W_dec,
                                               float* __restrict__ at2p, float* __restrict__ awf,
                                               float* __restrict__ zsum) {
    __shared__ __align__(16) float hs[8192];
    int tid = threadIdx.x;
    for (int i = blockIdx.x * 256 + tid; i < 8192; i += 1024) awf[i] = 0.f;
    if (blockIdx.x == 0 && tid < 32) zsum[tid] = 0.f;
    for (int i = tid; i < 2048; i += 256) ((float4*)hs)[i] = ((const float4*)hst)[i];
    __syncthreads();
    int col = blockIdx.x * 64 + (tid & 63), bg = tid >> 6;
    float acc[8] = {0.f,0.f,0.f,0.f,0.f,0.f,0.f,0.f};
    for (int k = 0; k < 256; ++k) {
        float w = W_dec[(size_t)k * 256 + col];
#pragma unroll
        for (int bi = 0; bi < 8; ++bi) acc[bi] += hs[(bg * 8 + bi) * 256 + k] * w;
    }
#pragma unroll
    for (int bi = 0; bi < 8; ++bi) {
        int b = bg * 8 + bi;
        at2p[((size_t)(b * 8 + 0)) * 256 + col] = acc[bi];
#pragma unroll
        for (int ct = 1; ct < 8; ++ct) at2p[((size_t)(b * 8 + ct)) * 256 + col] = 0.f;
    }
}

// ---------------- att1h = bf16(info_sorted @ W_enc + b_enc); infoh = bf16(info_sorted) ----------------
__global__ __launch_bounds__(256) void k_att1(const float* __restrict__ info, const int* __restrict__ ord,
                                              const float* __restrict__ W, const float* __restrict__ bias,
                                              unsigned short* __restrict__ att1h,
                                              unsigned short* __restrict__ infoh) {
    __shared__ __align__(16) float xsT[256 * 36];
    int tid = threadIdx.x;
    int r0 = blockIdx.x * 32;
    int b = r0 >> 10, p0 = r0 & 1023;
    const float* src = info + (size_t)ord[b] * INFLAT + (size_t)p0 * 256;
    for (int idx = tid; idx < 2048; idx += 256) {
        int r = idx >> 6, kq = idx & 63;
        float4 v = *(const float4*)&src[r * 256 + kq * 4];
        xsT[(kq * 4 + 0) * 36 + r] = v.x;
        xsT[(kq * 4 + 1) * 36 + r] = v.y;
        xsT[(kq * 4 + 2) * 36 + r] = v.z;
        xsT[(kq * 4 + 3) * 36 + r] = v.w;
    }
    __syncthreads();
#pragma unroll 4
    for (int r = 0; r < 32; ++r)
        infoh[(size_t)(r0 + r) * 256 + tid] = f2bf(xsT[tid * 36 + r]);
    float acc[32];
#pragma unroll
    for (int r = 0; r < 32; ++r) acc[r] = 0.f;
    for (int k = 0; k < 256; ++k) {
        float w = W[k * 256 + tid];
        const float4* xr = (const float4*)&xsT[k * 36];
#pragma unroll
        for (int rq = 0; rq < 8; ++rq) {
            float4 x4 = xr[rq];
            acc[rq * 4 + 0] += x4.x * w;
            acc[rq * 4 + 1] += x4.y * w;
            acc[rq * 4 + 2] += x4.z * w;
            acc[rq * 4 + 3] += x4.w * w;
        }
    }
    float bj = bias[tid];
#pragma unroll
    for (int r = 0; r < 32; ++r)
        att1h[(size_t)(r0 + r) * 256 + tid] = f2bf(acc[r] + bj);
}

// ---------------- fused steps kernel ----------------
struct KArgs {
    const float *info, *emb, *W_dec, *b_dec, *W_full, *b_full;
    const float *W_i, *W_f, *W_o, *W_g1, *W_g2;
    const float *b_i, *b_f, *b_o, *b_g1, *b_g2;
    const float *W_mlp, *b_mlp, *W_fc, *b_fc;
    const int *caps;
    const unsigned short *att1h, *infoh;
    float *expe, *zsum, *awf, *gsp, *hst, *cst0, *Cst0, *cst1, *Cst1, *at2p;
    const int *ord, *slp;
    int *root, *slots;
    float *out_pred, *out_alpha;
};

// pred from bf16 h staged in scratch (S16)
__device__ void pred_task2(const KArgs& a, unsigned short* hb, int tile, int tm1) {
    int tid = threadIdx.x;
    for (int i = tid; i < 8192; i += 256) hb[i] = f2bf(agload(&a.hst[i]));
    __syncthreads();
    int col = tile * 64 + (tid & 63), bg = tid >> 6;
    if (col >= Vz) return;
    float acc[8] = {0.f, 0.f, 0.f, 0.f, 0.f, 0.f, 0.f, 0.f};
    for (int jq = 0; jq < 64; ++jq) {
        float w0 = a.W_fc[(size_t)(jq * 4 + 0) * Vz + col];
        float w1 = a.W_fc[(size_t)(jq * 4 + 1) * Vz + col];
        float w2 = a.W_fc[(size_t)(jq * 4 + 2) * Vz + col];
        float w3 = a.W_fc[(size_t)(jq * 4 + 3) * Vz + col];
#pragma unroll
        for (int bi = 0; bi < 8; ++bi) {
            uint2 u = *(const uint2*)&hb[(bg * 8 + bi) * 256 + jq * 4];
            acc[bi] += bfl(u.x) * w0 + bfh(u.x) * w1 + bfl(u.y) * w2 + bfh(u.y) * w3;
        }
    }
    float bv = a.b_fc[col];
#pragma unroll
    for (int bi = 0; bi < 8; ++bi) {
        int b = bg * 8 + bi;
        float r = (a.slp[b] > tm1) ? (acc[bi] + bv) : 0.f;
        a.out_pred[((size_t)b * TMz + tm1) * Vz + col] = r;
    }
}

// LDS (80 KB): [0..32767] attB (swizzled bf16 att1h slice), [32768..65535] infB (linear bf16 info slice),
// [65536..81919] scratch union: PA floats F[0..1343]; PB x/h bf16 stage (8192 ushorts); PC floats F[0..1087]
__global__ __launch_bounds__(256, 2) void k_steps(KArgs a) {
    __shared__ __align__(16) unsigned char smem[81920];
    unsigned char* attB = smem;
    unsigned char* infB = smem + 32768;
    float* F = (float*)(smem + 65536);
    unsigned short* S16 = (unsigned short*)(smem + 65536);

    int bid = blockIdx.x, tid = threadIdx.x;
    int b = bid >> 4, sub = bid & 15;
    int gen = 0;

    // persistent staging of this block's att1h/infoh slice (once)
    {
        const unsigned short* ag = a.att1h + (size_t)(b * 1024 + sub * 64) * 256;
        const unsigned short* ig = a.infoh + (size_t)(b * 1024 + sub * 64) * 256;
        for (int idx = tid; idx < 2048; idx += 256) {
            int r = idx >> 5, qc = idx & 31;
            uint4 v = *(const uint4*)(ag + (size_t)r * 256 + qc * 8);
            *(uint4*)(attB + r * 512 + ((qc ^ (r & 7)) << 4)) = v;
            uint4 w2 = *(const uint4*)(ig + (size_t)r * 256 + qc * 8);
            *(uint4*)(infB + idx * 16) = w2;
        }
    }
    __syncthreads();

    for (int t = 0; t < TMz; ++t) {
        // ---------- PA: at2 + e + expe + zsum + awf (512 blocks, LDS-resident data) ----------
        {
            float v = a.b_dec[tid];
#pragma unroll
            for (int ct = 0; ct < 8; ++ct) v += agload(&a.at2p[((size_t)(b * 8 + ct)) * 256 + tid]);
            F[tid] = v;                 // at2
            F[256 + tid] = a.W_full[tid];
            __syncthreads();
            int pl = tid & 63, kq = tid >> 6;
            float part = 0.f;
#pragma unroll
            for (int q = 0; q < 8; ++q) {
                int c = kq * 8 + q;
                uint4 u = *(const uint4*)(attB + pl * 512 + ((c ^ (pl & 7)) << 4));
                const float* A = F + kq * 64 + q * 8;
                const float* W = F + 256 + kq * 64 + q * 8;
                part += fmaxf(bfl(u.x) + A[0], 0.f) * W[0];
                part += fmaxf(bfh(u.x) + A[1], 0.f) * W[1];
                part += fmaxf(bfl(u.y) + A[2], 0.f) * W[2];
                part += fmaxf(bfh(u.y) + A[3], 0.f) * W[3];
                part += fmaxf(bfl(u.z) + A[4], 0.f) * W[4];
                part += fmaxf(bfh(u.z) + A[5], 0.f) * W[5];
                part += fmaxf(bfl(u.w) + A[6], 0.f) * W[6];
                part += fmaxf(bfh(u.w) + A[7], 0.f) * W[7];
            }
            F[512 + kq * 64 + pl] = part;
            __syncthreads();
            if (tid < 64) {
                float e = F[512 + tid] + F[576 + tid] + F[640 + tid] + F[704 + tid] + a.b_full[0];
                float ex = expf(e);
                agstore(&a.expe[b * 1024 + sub * 64 + tid], ex);
                F[768 + tid] = ex;
                float s = ex;
                s += __shfl_down(s, 32); s += __shfl_down(s, 16); s += __shfl_down(s, 8);
                s += __shfl_down(s, 4);  s += __shfl_down(s, 2);  s += __shfl_down(s, 1);
                if (tid == 0) agadd(&a.zsum[b], s);
            }
            __syncthreads();
            int gg = tid >> 7, c2 = tid & 127;
            const unsigned char* ib = infB + gg * 512 + c2 * 4;
            const float* ex = F + 768;
            float a0 = 0.f, a1 = 0.f;
#pragma unroll
            for (int i = 0; i < 32; ++i) {
                unsigned int u = *(const unsigned int*)(ib + i * 1024);
                float ev = ex[i * 2 + gg];
                a0 += ev * bfl(u);
                a1 += ev * bfh(u);
            }
            F[832 + gg * 256 + c2 * 2]     = a0;
            F[832 + gg * 256 + c2 * 2 + 1] = a1;
            __syncthreads();
            agadd(&a.awf[b * 256 + tid], F[832 + tid] + F[1088 + tid]);
        }
        gbar(a.slots, a.root, ++gen);

        // ---------- PB: gates(0..79) | alpha(80..111) | pred(112..268) ----------
        if (bid < 80) {
            int g = bid / 16, s16 = bid % 16;
            int ct = s16 >> 2, kc = s16 & 3;
            const float* Wg = (g == 0) ? a.W_i : (g == 1) ? a.W_f : (g == 2) ? a.W_o : (g == 3) ? a.W_g1 : a.W_g2;
            for (int idx = tid; idx < 8192; idx += 256) {
                int b2 = idx >> 8, kk = idx & 255;
                float v;
                if (kc == 0) {
                    int cap = a.caps[a.ord[b2] * Tz + t];
                    v = a.emb[(size_t)cap * 512 + kk];
                } else if (kc == 1) {
                    int cap = a.caps[a.ord[b2] * Tz + t];
                    v = a.emb[(size_t)cap * 512 + 256 + kk];
                } else if (kc == 2) {
                    v = agload(&a.awf[b2 * 256 + kk]);   // raw, scaled after GEMV
                } else {
                    v = agload(&a.hst[b2 * 256 + kk]);
                }
                S16[idx] = f2bf(v);
            }
            __syncthreads();
            int col = ct * 64 + (tid & 63), bg = tid >> 6;
            float acc[8] = {0.f,0.f,0.f,0.f,0.f,0.f,0.f,0.f};
            int wbase = kc * 256;
            for (int kk = 0; kk < 256; kk += 4) {
                float w0 = Wg[(size_t)(wbase + kk + 0) * 256 + col];
                float w1 = Wg[(size_t)(wbase + kk + 1) * 256 + col];
                float w2 = Wg[(size_t)(wbase + kk + 2) * 256 + col];
                float w3 = Wg[(size_t)(wbase + kk + 3) * 256 + col];
#pragma unroll
                for (int bi = 0; bi < 8; ++bi) {
                    uint2 u = *(const uint2*)&S16[(bg * 8 + bi) * 256 + kk];
                    acc[bi] += bfl(u.x) * w0 + bfh(u.x) * w1 + bfl(u.y) * w2 + bfh(u.y) * w3;
                }
            }
            if (kc == 2) {
#pragma unroll
                for (int bi = 0; bi < 8; ++bi) {
                    float Z = agload(&a.zsum[bg * 8 + bi]);
                    acc[bi] *= (1.0f / Z);
                }
            }
#pragma unroll
            for (int bi = 0; bi < 8; ++bi)
                agstore(&a.gsp[((size_t)((g * 4 + kc) * 32 + bg * 8 + bi)) * 256 + col], acc[bi]);
        } else if (bid < 112) {
            int bb = bid - 80;
            float Z = agload(&a.zsum[bb]);
            float invZ = 1.0f / Z;
            float am = (a.slp[bb] > t) ? invZ : 0.f;
            float* oal = a.out_alpha + ((size_t)bb * TMz + t) * 1024;
            for (int p = tid; p < 1024; p += 256) oal[p] = agload(&a.expe[bb * 1024 + p]) * am;
        } else if (t > 0 && bid < 269) {
            pred_task2(a, S16, bid - 112, t - 1);
        }
        gbar(a.slots, a.root, ++gen);

        // ---------- PC: cell + mlp + h + at2p + awf/zsum zero (256 blocks: b x ct8) ----------
        if (bid < 256) {
            int bb = bid >> 3, ct = bid & 7;
            int j = tid;
            const float* csOld = (t & 1) ? a.cst1 : a.cst0;
            const float* CsOld = (t & 1) ? a.Cst1 : a.Cst0;
            float* csNew = (t & 1) ? a.cst0 : a.cst1;
            float* CsNew = (t & 1) ? a.Cst0 : a.Cst1;
            float gs[5];
#pragma unroll
            for (int g = 0; g < 5; ++g) {
                float s = 0.f;
#pragma unroll
                for (int kc = 0; kc < 4; ++kc)
                    s += agload(&a.gsp[((size_t)((g * 4 + kc) * 32 + bb)) * 256 + j]);
                gs[g] = s;
            }
            gs[0] += a.b_i[j]; gs[1] += a.b_f[j]; gs[2] += a.b_o[j];
            gs[3] += a.b_g1[j]; gs[4] += a.b_g2[j];
            float iv = sigm(gs[0]), fv = sigm(gs[1]), ov = sigm(gs[2]);
            float g1 = tanhf(gs[3]), g2 = tanhf(gs[4]);
            float nc = fv * agload(&csOld[bb * 256 + j]) + iv * g1;
            float nC = fv * agload(&CsOld[bb * 256 + j]) + iv * g2;
            if (ct == 0) {
                agstore(&csNew[bb * 256 + j], nc);
                agstore(&CsNew[bb * 256 + j], nC);
            }
            if (ct == 1 && tid == 0) agstore(&a.zsum[bb], 0.f);
            F[j] = nc;
            F[256 + j] = nC;
            F[512 + j] = ov;
            __syncthreads();
            int colL = tid & 31, kth = tid >> 5;
            int col = ct * 32 + colL;
            float part = 0.f;
            const float* wm = a.W_mlp + col;
            for (int i = 0; i < 64; ++i) {
                int k = kth * 64 + i;
                part += F[k] * wm[(size_t)k * 256];
            }
            F[768 + colL * 9 + kth] = part;
            __syncthreads();
            if (tid < 32) {
                int c2 = ct * 32 + tid;
                float m = a.b_mlp[c2];
#pragma unroll
                for (int kk = 0; kk < 8; ++kk) m += F[768 + tid * 9 + kk];
                float hv = F[512 + c2] * tanhf(m);
                agstore(&a.hst[bb * 256 + c2], hv);
                F[1056 + tid] = hv;
                agstore(&a.awf[bb * 256 + c2], 0.f);
            }
            __syncthreads();
            float acc = 0.f;
            const float* wd = a.W_dec + (size_t)(ct * 32) * 256 + tid;
#pragma unroll
            for (int kk = 0; kk < 32; ++kk) acc += F[1056 + kk] * wd[(size_t)kk * 256];
            agstore(&a.at2p[((size_t)(bb * 8 + ct)) * 256 + tid], acc);
        }
        gbar(a.slots, a.root, ++gen);
    }

    // epilogue: pred for t = 18
    if (bid >= 112 && bid < 269) pred_task2(a, S16, bid - 112, TMz - 1);
}

extern "C" void kernel_launch(void* const* d_in, const int* in_sizes, int n_in,
                              void* d_out, int out_size, void* d_ws, size_t ws_size,
                              hipStream_t stream) {
    const float* info  = (const float*)d_in[0];
    const float* rel   = (const float*)d_in[1];
    const int*   caps  = (const int*)d_in[2];
    const int*   lens  = (const int*)d_in[3];
    const float* emb   = (const float*)d_in[4];
    const float* W_enc = (const float*)d_in[5];
    const float* b_enc = (const float*)d_in[6];
    const float* W_dec = (const float*)d_in[7];
    const float* b_dec = (const float*)d_in[8];
    const float* W_full= (const float*)d_in[9];
    const float* b_full= (const float*)d_in[10];
    const float* W_i   = (const float*)d_in[11];
    const float* b_i   = (const float*)d_in[12];
    const float* W_f   = (const float*)d_in[13];
    const float* b_f   = (const float*)d_in[14];
    const float* W_o   = (const float*)d_in[15];
    const float* b_o   = (const float*)d_in[16];
    const float* W_g1  = (const float*)d_in[17];
    const float* b_g1  = (const float*)d_in[18];
    const float* W_g2  = (const float*)d_in[19];
    const float* b_g2  = (const float*)d_in[20];
    const float* W_mlp = (const float*)d_in[21];
    const float* b_mlp = (const float*)d_in[22];
    const float* W_fc  = (const float*)d_in[25];
    const float* b_fc  = (const float*)d_in[26];
    const float* W_ih  = (const float*)d_in[27];
    const float* b_ih  = (const float*)d_in[28];
    const float* W_ic  = (const float*)d_in[29];
    const float* b_ic  = (const float*)d_in[30];
    const float* W_iC  = (const float*)d_in[31];
    const float* b_iC  = (const float*)d_in[32];

    float* out = (float*)d_out;
    float* out_pred  = out;
    float* out_alpha = out + (size_t)Bz * TMz * Vz;
    float* out_order = out_alpha + (size_t)Bz * TMz * 1024;

    float* w = (float*)d_ws;
    float* ph   = w + WS_PH;
    float* pcp  = w + WS_PC;
    unsigned short* att1h = (unsigned short*)(w + WS_ATT1H);
    unsigned short* infoh = (unsigned short*)(w + WS_INFOH);
    float* expe = w + WS_EXPE;
    float* zsum = w + WS_ZSUM;
    float* awf  = w + WS_AWF;
    float* gsp  = w + WS_GSP;
    float* hst  = w + WS_HST;
    float* cst0 = w + WS_CST0;
    float* Cst0 = w + WS_CSTB0;
    float* cst1 = w + WS_CST1;
    float* Cst1 = w + WS_CSTB1;
    float* at2p = w + WS_AT2P;
    int*   ordp = (int*)(w + WS_INTS);
    int*   slp  = ordp + 32;
    int*   barmem = ordp + 64;
    float* pC   = w + WS_PCHC;

    k_sort<<<1, 64, 0, stream>>>(lens, out_order, ordp, slp, barmem);
    k_gemv2<<<512, 256, 0, stream>>>(info, ordp, W_ih, W_ic, ph, pcp);
    k_gemvC<<<128, 256, 0, stream>>>(rel, ordp, W_iC, pC);
    k_reduce3<<<96, 256, 0, stream>>>(ph, pcp, pC, b_ih, b_ic, b_iC, hst, cst0, Cst0);
    k_init2<<<4, 256, 0, stream>>>(hst, W_dec, at2p, awf, zsum);
    k_att1<<<1024, 256, 0, stream>>>(info, ordp, W_enc, b_enc, att1h, infoh);

    KArgs ka;
    ka.info = info; ka.emb = emb; ka.W_dec = W_dec; ka.b_dec = b_dec;
    ka.W_full = W_full; ka.b_full = b_full;
    ka.W_i = W_i; ka.W_f = W_f; ka.W_o = W_o; ka.W_g1 = W_g1; ka.W_g2 = W_g2;
    ka.b_i = b_i; ka.b_f = b_f; ka.b_o = b_o; ka.b_g1 = b_g1; ka.b_g2 = b_g2;
    ka.W_mlp = W_mlp; ka.b_mlp = b_mlp; ka.W_fc = W_fc; ka.b_fc = b_fc;
    ka.caps = caps;
    ka.att1h = att1h; ka.infoh = infoh;
    ka.expe = expe; ka.zsum = zsum; ka.awf = awf;
    ka.gsp = gsp; ka.hst = hst;
    ka.cst0 = cst0; ka.Cst0 = Cst0; ka.cst1 = cst1; ka.Cst1 = Cst1;
    ka.at2p = at2p;
    ka.ord = ordp; ka.slp = slp;
    ka.root = barmem; ka.slots = barmem + 64;
    ka.out_pred = out_pred; ka.out_alpha = out_alpha;

    k_steps<<<NBLK, 256, 0, stream>>>(ka);
}